// Round 2
// baseline (661.005 us; speedup 1.0000x reference)
//
#include <hip/hip_runtime.h>
#include <stdint.h>

#define DEVI __device__ __forceinline__

typedef __attribute__((ext_vector_type(8))) short bf16x8;
typedef __attribute__((ext_vector_type(4))) float f32x4;
typedef unsigned short u16;

constexpr int EMB = 1024, SEQ = 2048, NBATCH = 4, NTOK = 8192;
constexpr int HEADS = 16, HD = 64, INNER = 4096;

DEVI u16 f2b(float f) {
  uint32_t u = __float_as_uint(f);
  return (u16)((u + 0x7FFFu + ((u >> 16) & 1u)) >> 16);
}

DEVI void gload16(const void* g, void* l) {
  __builtin_amdgcn_global_load_lds(
      (const __attribute__((address_space(1))) void*)g,
      (__attribute__((address_space(3))) void*)l, 16, 0, 0);
}

// ---------------- elementwise fp32 -> bf16 ----------------
__global__ __launch_bounds__(256) void k_cvt(const float* __restrict__ src,
                                             u16* __restrict__ dst, int n4) {
  int i = blockIdx.x * 256 + threadIdx.x;
  if (i >= n4) return;
  float4 v = ((const float4*)src)[i];
  ushort4 o = {f2b(v.x), f2b(v.y), f2b(v.z), f2b(v.w)};
  ((ushort4*)dst)[i] = o;
}

// ------------- transpose + convert: dst[n][k] = bf16(src[k][n]) -------------
__global__ __launch_bounds__(256) void k_cvtT(const float* __restrict__ src,
                                              u16* __restrict__ dst, int K, int N) {
  __shared__ float t[32][33];
  int bk = blockIdx.x % (K >> 5), bn = blockIdx.x / (K >> 5);
  int tx = threadIdx.x & 31, ty = threadIdx.x >> 5;
#pragma unroll
  for (int i = 0; i < 4; i++)
    t[ty + i * 8][tx] = src[(size_t)(bk * 32 + ty + i * 8) * N + bn * 32 + tx];
  __syncthreads();
#pragma unroll
  for (int i = 0; i < 4; i++)
    dst[(size_t)(bn * 32 + ty + i * 8) * K + bk * 32 + tx] = f2b(t[tx][ty + i * 8]);
}

// ---------------- GEMM: C = A[M][K] * BT[N][K]^T, bf16 in, fp32 acc ----------
// EPI 0: QKV scatter (ob0=q [bh][s][d], ob1=k [bh][s][d], ob2=vT [bh][d][s])
// EPI 1: of0 = acc + bias[col] + res[row][col]      (fp32 out, N==1024)
// EPI 2: ob0 = bf16(relu(acc + bias[col]))
// EPI 3: of0 = acc + bias[col]                      (fp32 out)
template <int EPI>
__global__ __launch_bounds__(256, 2) void k_gemm(
    const u16* __restrict__ A, const u16* __restrict__ BT, int M, int N, int K,
    u16* __restrict__ ob0, u16* __restrict__ ob1, u16* __restrict__ ob2,
    float* __restrict__ of0, const float* __restrict__ bias,
    const float* __restrict__ res) {
  __shared__ u16 As[128 * 64];
  __shared__ u16 Bs[128 * 64];
  const int tid = threadIdx.x;
  const int lane = tid & 63, w = tid >> 6;
  const int wr = w >> 1, wc = w & 1;
  const int g = lane >> 4, c = lane & 15;
  const int nbx = N >> 7;
  const int by = blockIdx.x / nbx, bx = blockIdx.x % nbx;
  const int row0 = by << 7, col0 = bx << 7;

  const f32x4 z4 = {0.f, 0.f, 0.f, 0.f};
  f32x4 acc[4][4];
#pragma unroll
  for (int m = 0; m < 4; m++)
#pragma unroll
    for (int n = 0; n < 4; n++) acc[m][n] = z4;

  for (int k0 = 0; k0 < K; k0 += 64) {
    __syncthreads();  // all waves done reading previous tile
#pragma unroll
    for (int i = 0; i < 4; i++) {
      int s = tid + (i << 8);
      int r = s >> 3, cb = s & 7;
      gload16(A + (size_t)(row0 + r) * K + (k0 + ((cb ^ (r & 7)) << 3)),
              (char*)As + s * 16);
    }
#pragma unroll
    for (int i = 0; i < 4; i++) {
      int s = tid + (i << 8);
      int r = s >> 3, cb = s & 7;
      gload16(BT + (size_t)(col0 + r) * K + (k0 + ((cb ^ (r & 7)) << 3)),
              (char*)Bs + s * 16);
    }
    __syncthreads();  // drains vmcnt, LDS visible
#pragma unroll
    for (int kk = 0; kk < 2; kk++) {
      bf16x8 af[4], bfr[4];
#pragma unroll
      for (int m = 0; m < 4; m++) {
        int r = wr * 64 + m * 16 + c;
        int off = (r * 128 + kk * 64 + g * 16) ^ ((r & 7) << 4);
        af[m] = *(const bf16x8*)((const char*)As + off);
      }
#pragma unroll
      for (int n = 0; n < 4; n++) {
        int r = wc * 64 + n * 16 + c;
        int off = (r * 128 + kk * 64 + g * 16) ^ ((r & 7) << 4);
        bfr[n] = *(const bf16x8*)((const char*)Bs + off);
      }
#pragma unroll
      for (int m = 0; m < 4; m++)
#pragma unroll
        for (int n = 0; n < 4; n++)
          acc[m][n] =
              __builtin_amdgcn_mfma_f32_16x16x32_bf16(af[m], bfr[n], acc[m][n], 0, 0, 0);
    }
  }

#pragma unroll
  for (int m = 0; m < 4; m++) {
#pragma unroll
    for (int n = 0; n < 4; n++) {
      int ocol = col0 + wc * 64 + n * 16 + c;
      int orow_base = row0 + wr * 64 + m * 16 + 4 * g;
      if constexpr (EPI == 0) {
        int which = ocol >> 10, rem = ocol & 1023;
        int h = rem >> 6, d = rem & 63;
#pragma unroll
        for (int r = 0; r < 4; r++) {
          int orow = orow_base + r;
          int b = orow >> 11, s = orow & 2047;
          int bh = b * HEADS + h;
          u16 val = f2b(acc[m][n][r]);
          if (which == 0)
            ob0[((size_t)bh * SEQ + s) * HD + d] = val;
          else if (which == 1)
            ob1[((size_t)bh * SEQ + s) * HD + d] = val;
          else
            ob2[((size_t)bh * HD + d) * SEQ + s] = val;
        }
      } else if constexpr (EPI == 1) {
        float bia = bias[ocol];
#pragma unroll
        for (int r = 0; r < 4; r++) {
          int orow = orow_base + r;
          of0[(size_t)orow * N + ocol] =
              acc[m][n][r] + bia + res[(size_t)orow * N + ocol];
        }
      } else if constexpr (EPI == 2) {
        float bia = bias[ocol];
#pragma unroll
        for (int r = 0; r < 4; r++) {
          int orow = orow_base + r;
          float v = acc[m][n][r] + bia;
          ob0[(size_t)orow * N + ocol] = f2b(v > 0.f ? v : 0.f);
        }
      } else {
        float bia = bias[ocol];
#pragma unroll
        for (int r = 0; r < 4; r++) {
          int orow = orow_base + r;
          of0[(size_t)orow * N + ocol] = acc[m][n][r] + bia;
        }
      }
    }
  }
}

// ---------------- flash attention: 4 waves x 16 q-rows, KVBLK=64 -------------
__global__ __launch_bounds__(256, 2) void k_attn(const u16* __restrict__ q,
                                                 const u16* __restrict__ kb,
                                                 const u16* __restrict__ vT,
                                                 u16* __restrict__ attn) {
  __shared__ u16 Ks[64 * 64];       // [key][d]
  __shared__ u16 Vs[64 * 64];       // V^T tile: [d][key]
  __shared__ u16 Ps[4][16 * 64];    // per-wave P: [qrow][key]
  const int tid = threadIdx.x, lane = tid & 63, w = tid >> 6;
  const int g = lane >> 4, c = lane & 15;
  const int blk = blockIdx.x;
  const int bh = blk >> 5, qb = blk & 31;
  const int b = bh >> 4, h = bh & 15;
  const u16* qh = q + (size_t)bh * SEQ * HD;
  const u16* kh = kb + (size_t)bh * SEQ * HD;
  const u16* vh = vT + (size_t)bh * HD * SEQ;
  const int qr = qb * 64 + w * 16 + c;  // A-frag row for this lane
  bf16x8 qf0 = *(const bf16x8*)(qh + (size_t)qr * HD + 8 * g);
  bf16x8 qf1 = *(const bf16x8*)(qh + (size_t)qr * HD + 32 + 8 * g);

  const f32x4 z4 = {0.f, 0.f, 0.f, 0.f};
  f32x4 O[4];
#pragma unroll
  for (int n = 0; n < 4; n++) O[n] = z4;
  float mI[4] = {-1e30f, -1e30f, -1e30f, -1e30f};
  float lI[4] = {0.f, 0.f, 0.f, 0.f};
  u16* pw = &Ps[w][0];

  for (int kt = 0; kt < SEQ / 64; kt++) {
    const int kv0 = kt * 64;
    __syncthreads();
#pragma unroll
    for (int i = 0; i < 2; i++) {
      int s = tid + (i << 8);
      int r = s >> 3, cb = s & 7;
      gload16(kh + (size_t)(kv0 + r) * HD + ((cb ^ (r & 7)) << 3), (char*)Ks + s * 16);
    }
#pragma unroll
    for (int i = 0; i < 2; i++) {
      int s = tid + (i << 8);
      int r = s >> 3, cb = s & 7;
      gload16(vh + (size_t)r * SEQ + kv0 + ((cb ^ (r & 7)) << 3), (char*)Vs + s * 16);
    }
    __syncthreads();

    // S = Q K^T : rows 4g+r (q), cols 16n+c (key)
    f32x4 sc[4];
#pragma unroll
    for (int n = 0; n < 4; n++) {
      int r = n * 16 + c;
      int off0 = (r * 128 + g * 16) ^ ((r & 7) << 4);
      int off1 = (r * 128 + 64 + g * 16) ^ ((r & 7) << 4);
      bf16x8 kf0 = *(const bf16x8*)((const char*)Ks + off0);
      bf16x8 kf1 = *(const bf16x8*)((const char*)Ks + off1);
      f32x4 a = z4;
      a = __builtin_amdgcn_mfma_f32_16x16x32_bf16(qf0, kf0, a, 0, 0, 0);
      a = __builtin_amdgcn_mfma_f32_16x16x32_bf16(qf1, kf1, a, 0, 0, 0);
      sc[n] = a;
    }
    float mNew[4], alpha[4];
#pragma unroll
    for (int r = 0; r < 4; r++) {
      float t = fmaxf(fmaxf(sc[0][r], sc[1][r]), fmaxf(sc[2][r], sc[3][r]));
      t *= 0.125f;
#pragma unroll
      for (int msk = 1; msk < 16; msk <<= 1) t = fmaxf(t, __shfl_xor(t, msk));
      mNew[r] = fmaxf(mI[r], t);
      alpha[r] = __expf(mI[r] - mNew[r]);
      mI[r] = mNew[r];
    }
    float rsum[4] = {0.f, 0.f, 0.f, 0.f};
#pragma unroll
    for (int n = 0; n < 4; n++) {
#pragma unroll
      for (int r = 0; r < 4; r++) {
        float p = __expf(sc[n][r] * 0.125f - mNew[r]);
        rsum[r] += p;
        int prow = 4 * g + r;
        int off = (prow * 128 + (16 * n + c) * 2) ^ ((prow & 7) << 4);
        *(u16*)((char*)pw + off) = f2b(p);
      }
    }
#pragma unroll
    for (int r = 0; r < 4; r++) {
      float t = rsum[r];
#pragma unroll
      for (int msk = 1; msk < 16; msk <<= 1) t += __shfl_xor(t, msk);
      lI[r] = lI[r] * alpha[r] + t;
    }
#pragma unroll
    for (int n = 0; n < 4; n++)
#pragma unroll
      for (int r = 0; r < 4; r++) O[n][r] *= alpha[r];

    // PV: A = P (rows=c), B = V^T tile
    bf16x8 pa0, pa1;
    {
      int off0 = (c * 128 + g * 16) ^ ((c & 7) << 4);
      int off1 = (c * 128 + 64 + g * 16) ^ ((c & 7) << 4);
      pa0 = *(const bf16x8*)((const char*)pw + off0);
      pa1 = *(const bf16x8*)((const char*)pw + off1);
    }
#pragma unroll
    for (int n = 0; n < 4; n++) {
      int r = n * 16 + c;
      int off0 = (r * 128 + g * 16) ^ ((r & 7) << 4);
      int off1 = (r * 128 + 64 + g * 16) ^ ((r & 7) << 4);
      bf16x8 vf0 = *(const bf16x8*)((const char*)Vs + off0);
      bf16x8 vf1 = *(const bf16x8*)((const char*)Vs + off1);
      O[n] = __builtin_amdgcn_mfma_f32_16x16x32_bf16(pa0, vf0, O[n], 0, 0, 0);
      O[n] = __builtin_amdgcn_mfma_f32_16x16x32_bf16(pa1, vf1, O[n], 0, 0, 0);
    }
  }
#pragma unroll
  for (int n = 0; n < 4; n++) {
#pragma unroll
    for (int r = 0; r < 4; r++) {
      int s = qb * 64 + w * 16 + 4 * g + r;
      int col = h * HD + 16 * n + c;
      attn[((size_t)(b * SEQ + s)) * EMB + col] = f2b(O[n][r] / lI[r]);
    }
  }
}

// ---------------- LayerNorm kernels ----------------
__global__ __launch_bounds__(256) void k_ln1(const float* __restrict__ y,
                                             const float* __restrict__ gw,
                                             const float* __restrict__ bw,
                                             float* __restrict__ hf,
                                             u16* __restrict__ hb) {
  const int row = blockIdx.x, tid = threadIdx.x, lane = tid & 63, w = tid >> 6;
  const float4 v = ((const float4*)(y + (size_t)row * EMB))[tid];
  float s = v.x + v.y + v.z + v.w;
  float s2 = v.x * v.x + v.y * v.y + v.z * v.z + v.w * v.w;
#pragma unroll
  for (int m = 1; m < 64; m <<= 1) {
    s += __shfl_xor(s, m);
    s2 += __shfl_xor(s2, m);
  }
  __shared__ float rs_[4], rq_[4];
  if (lane == 0) { rs_[w] = s; rq_[w] = s2; }
  __syncthreads();
  s = rs_[0] + rs_[1] + rs_[2] + rs_[3];
  s2 = rq_[0] + rq_[1] + rq_[2] + rq_[3];
  const float mu = s * (1.f / EMB);
  const float var = s2 * (1.f / EMB) - mu * mu;
  const float rstd = rsqrtf(var + 1e-5f);
  const float4 gg = ((const float4*)gw)[tid];
  const float4 bb = ((const float4*)bw)[tid];
  float4 o;
  o.x = (v.x - mu) * rstd * gg.x + bb.x;
  o.y = (v.y - mu) * rstd * gg.y + bb.y;
  o.z = (v.z - mu) * rstd * gg.z + bb.z;
  o.w = (v.w - mu) * rstd * gg.w + bb.w;
  ((float4*)(hf + (size_t)row * EMB))[tid] = o;
  ushort4 ob = {f2b(o.x), f2b(o.y), f2b(o.z), f2b(o.w)};
  ((ushort4*)(hb + (size_t)row * EMB))[tid] = ob;
}

__global__ __launch_bounds__(256) void k_ln2(const float* __restrict__ hf,
                                             const float* __restrict__ z,
                                             const float* __restrict__ gw,
                                             const float* __restrict__ bw,
                                             float* __restrict__ outp) {
  const int row = blockIdx.x, tid = threadIdx.x, lane = tid & 63, w = tid >> 6;
  float4 v = ((const float4*)(hf + (size_t)row * EMB))[tid];
  const float4 zz = ((const float4*)(z + (size_t)row * EMB))[tid];
  v.x += zz.x; v.y += zz.y; v.z += zz.z; v.w += zz.w;
  float s = v.x + v.y + v.z + v.w;
  float s2 = v.x * v.x + v.y * v.y + v.z * v.z + v.w * v.w;
#pragma unroll
  for (int m = 1; m < 64; m <<= 1) {
    s += __shfl_xor(s, m);
    s2 += __shfl_xor(s2, m);
  }
  __shared__ float rs_[4], rq_[4];
  if (lane == 0) { rs_[w] = s; rq_[w] = s2; }
  __syncthreads();
  s = rs_[0] + rs_[1] + rs_[2] + rs_[3];
  s2 = rq_[0] + rq_[1] + rq_[2] + rq_[3];
  const float mu = s * (1.f / EMB);
  const float var = s2 * (1.f / EMB) - mu * mu;
  const float rstd = rsqrtf(var + 1e-5f);
  const float4 gg = ((const float4*)gw)[tid];
  const float4 bb = ((const float4*)bw)[tid];
  float4 o;
  o.x = (v.x - mu) * rstd * gg.x + bb.x;
  o.y = (v.y - mu) * rstd * gg.y + bb.y;
  o.z = (v.z - mu) * rstd * gg.z + bb.z;
  o.w = (v.w - mu) * rstd * gg.w + bb.w;
  ((float4*)(outp + (size_t)row * EMB))[tid] = o;
}

extern "C" void kernel_launch(void* const* d_in, const int* in_sizes, int n_in,
                              void* d_out, int out_size, void* d_ws, size_t ws_size,
                              hipStream_t stream) {
  const float* x = (const float*)d_in[0];
  const float* Wq = (const float*)d_in[1];
  const float* Wk = (const float*)d_in[2];
  const float* Wv = (const float*)d_in[3];
  const float* Wo = (const float*)d_in[4];
  const float* bo = (const float*)d_in[5];
  const float* g1 = (const float*)d_in[6];
  const float* b1 = (const float*)d_in[7];
  const float* W1 = (const float*)d_in[8];
  const float* bf1 = (const float*)d_in[9];
  const float* W2 = (const float*)d_in[10];
  const float* bf2 = (const float*)d_in[11];
  const float* g2 = (const float*)d_in[12];
  const float* b2 = (const float*)d_in[13];
  float* out = (float*)d_out;

  char* ws = (char*)d_ws;
  size_t off = 0;
  auto alloc = [&](size_t bytes) {
    char* p = ws + off;
    off += (bytes + 255) & ~(size_t)255;
    return p;
  };
  u16* xb = (u16*)alloc((size_t)NTOK * EMB * 2);        // 16.8 MB
  u16* wqkvT = (u16*)alloc((size_t)3072 * 1024 * 2);    // 6.3 MB
  u16* qB = (u16*)alloc((size_t)NTOK * EMB * 2);        // 16.8 MB
  u16* kB = (u16*)alloc((size_t)NTOK * EMB * 2);        // 16.8 MB
  u16* vTB = (u16*)alloc((size_t)NTOK * EMB * 2);       // 16.8 MB
  u16* woT = (u16*)alloc((size_t)1024 * 1024 * 2);      // 2.1 MB
  u16* w1T = (u16*)alloc((size_t)4096 * 1024 * 2);      // 8.4 MB
  u16* w2T = (u16*)alloc((size_t)1024 * 4096 * 2);      // 8.4 MB
  float* y = (float*)alloc((size_t)NTOK * EMB * 4);     // 33.6 MB
  u16* ff1 = (u16*)alloc((size_t)NTOK * INNER * 2);     // 67.1 MB  (~193 MB total)
  // aliases over dead regions:
  u16* attn = xb;        // xb dead after QKV GEMM
  float* hf = (float*)qB;  // spans qB+kB (33.6 MB), dead after attention
  u16* hb = vTB;         // dead after attention
  float* z = y;          // y dead after LN1

  // conversions
  k_cvt<<<NTOK * EMB / 4 / 256, 256, 0, stream>>>(x, xb, NTOK * EMB / 4);
  k_cvtT<<<1024, 256, 0, stream>>>(Wq, wqkvT, 1024, 1024);
  k_cvtT<<<1024, 256, 0, stream>>>(Wk, wqkvT + 1048576, 1024, 1024);
  k_cvtT<<<1024, 256, 0, stream>>>(Wv, wqkvT + 2097152, 1024, 1024);
  k_cvtT<<<1024, 256, 0, stream>>>(Wo, woT, 1024, 1024);
  k_cvtT<<<4096, 256, 0, stream>>>(W1, w1T, 1024, 4096);
  k_cvtT<<<4096, 256, 0, stream>>>(W2, w2T, 4096, 1024);
  // QKV projection
  k_gemm<0><<<(NTOK / 128) * (3072 / 128), 256, 0, stream>>>(
      xb, wqkvT, NTOK, 3072, 1024, qB, kB, vTB, nullptr, nullptr, nullptr);
  // attention
  k_attn<<<64 * 32, 256, 0, stream>>>(qB, kB, vTB, attn);
  // out proj + bias + residual
  k_gemm<1><<<(NTOK / 128) * (1024 / 128), 256, 0, stream>>>(
      attn, woT, NTOK, 1024, 1024, nullptr, nullptr, nullptr, y, bo, x);
  // LN1
  k_ln1<<<NTOK, 256, 0, stream>>>(y, g1, b1, hf, hb);
  // FFN1 + relu
  k_gemm<2><<<(NTOK / 128) * (4096 / 128), 256, 0, stream>>>(
      hb, w1T, NTOK, 4096, 1024, ff1, nullptr, nullptr, nullptr, bf1, nullptr);
  // FFN2
  k_gemm<3><<<(NTOK / 128) * (1024 / 128), 256, 0, stream>>>(
      ff1, w2T, NTOK, 1024, 4096, nullptr, nullptr, nullptr, z, bf2, nullptr);
  // LN2 -> out
  k_ln2<<<NTOK, 256, 0, stream>>>(hf, z, g2, b2, out);
}

// Round 4
// 576.540 us; speedup vs baseline: 1.1465x; 1.1465x over previous
//
#include <hip/hip_runtime.h>
#include <stdint.h>

#define DEVI __device__ __forceinline__

typedef __attribute__((ext_vector_type(8))) short bf16x8;
typedef __attribute__((ext_vector_type(4))) short bf16x4;
typedef __attribute__((ext_vector_type(4))) float f32x4;
typedef unsigned short u16;
typedef uint32_t u32;

constexpr int EMB = 1024, SEQ = 2048, NTOK = 8192;
constexpr int HEADS = 16, HD = 64, INNER = 4096;

DEVI u16 f2b(float f) {
  u32 u = __float_as_uint(f);
  return (u16)((u + 0x7FFFu + ((u >> 16) & 1u)) >> 16);
}

// pack 2 f32 -> u32 of 2 bf16 (lo = first arg), RNE (guide T12 recipe, m240)
DEVI u32 pk2(float lo, float hi) {
  u32 r;
  asm("v_cvt_pk_bf16_f32 %0, %1, %2" : "=v"(r) : "v"(lo), "v"(hi));
  return r;
}

DEVI void gload16(const void* g, void* l) {
  __builtin_amdgcn_global_load_lds(
      (const __attribute__((address_space(1))) void*)g,
      (__attribute__((address_space(3))) void*)l, 16, 0, 0);
}

// bijective XCD-chunk swizzle; requires gridDim.x % 8 == 0 (all our grids are)
DEVI int xcd_swz(int bid, int nwg) { return (bid & 7) * (nwg >> 3) + (bid >> 3); }

// ---------------- elementwise fp32 -> bf16 ----------------
__global__ __launch_bounds__(256) void k_cvt(const float* __restrict__ src,
                                             u16* __restrict__ dst, int n4) {
  int i = blockIdx.x * 256 + threadIdx.x;
  if (i >= n4) return;
  float4 v = ((const float4*)src)[i];
  ushort4 o = {f2b(v.x), f2b(v.y), f2b(v.z), f2b(v.w)};
  ((ushort4*)dst)[i] = o;
}

// ------------- transpose + convert: dst[n][k] = bf16(src[k][n]) -------------
__global__ __launch_bounds__(256) void k_cvtT(const float* __restrict__ src,
                                              u16* __restrict__ dst, int K, int N) {
  __shared__ float t[32][33];
  int bk = blockIdx.x % (K >> 5), bn = blockIdx.x / (K >> 5);
  int tx = threadIdx.x & 31, ty = threadIdx.x >> 5;
#pragma unroll
  for (int i = 0; i < 4; i++)
    t[ty + i * 8][tx] = src[(size_t)(bk * 32 + ty + i * 8) * N + bn * 32 + tx];
  __syncthreads();
#pragma unroll
  for (int i = 0; i < 4; i++)
    dst[(size_t)(bn * 32 + ty + i * 8) * K + bk * 32 + tx] = f2b(t[tx][ty + i * 8]);
}

// ---------------- GEMM: C = A[M][K] * BT[N][K]^T, bf16 in, fp32 acc ----------
// EPI 0: QKV scatter (ob0=q*0.125 [bh][s][d], ob1=k [bh][s][d], ob2=vT [bh][d][s])
// EPI 1: of0 = acc + bias[col] + res[row][col]      (fp32 out)
// EPI 2: ob0 = bf16(relu(acc + bias[col]))
// EPI 3: of0 = acc + bias[col]                      (fp32 out)
template <int EPI>
__global__ __launch_bounds__(256, 2) void k_gemm(
    const u16* __restrict__ A, const u16* __restrict__ BT, int M, int N, int K,
    u16* __restrict__ ob0, u16* __restrict__ ob1, u16* __restrict__ ob2,
    float* __restrict__ of0, const float* __restrict__ bias,
    const float* __restrict__ res) {
  __shared__ u16 As[128 * 64];
  __shared__ u16 Bs[128 * 64];
  const int tid = threadIdx.x;
  const int lane = tid & 63, w = tid >> 6;
  const int wr = w >> 1, wc = w & 1;
  const int g = lane >> 4, c = lane & 15;
  const int nbx = N >> 7;
  const int bid = xcd_swz(blockIdx.x, gridDim.x);
  const int by = bid / nbx, bx = bid % nbx;
  const int row0 = by << 7, col0 = bx << 7;

  const f32x4 z4 = {0.f, 0.f, 0.f, 0.f};
  f32x4 acc[4][4];
#pragma unroll
  for (int m = 0; m < 4; m++)
#pragma unroll
    for (int n = 0; n < 4; n++) acc[m][n] = z4;

  for (int k0 = 0; k0 < K; k0 += 64) {
    __syncthreads();  // all waves done reading previous tile
#pragma unroll
    for (int i = 0; i < 4; i++) {
      int s = tid + (i << 8);
      int r = s >> 3, cb = s & 7;
      gload16(A + (size_t)(row0 + r) * K + (k0 + ((cb ^ (r & 7)) << 3)),
              (char*)As + s * 16);
    }
#pragma unroll
    for (int i = 0; i < 4; i++) {
      int s = tid + (i << 8);
      int r = s >> 3, cb = s & 7;
      gload16(BT + (size_t)(col0 + r) * K + (k0 + ((cb ^ (r & 7)) << 3)),
              (char*)Bs + s * 16);
    }
    __syncthreads();  // drains vmcnt, LDS visible
#pragma unroll
    for (int kk = 0; kk < 2; kk++) {
      bf16x8 af[4], bfr[4];
#pragma unroll
      for (int m = 0; m < 4; m++) {
        int r = wr * 64 + m * 16 + c;
        int off = (r * 128 + kk * 64 + g * 16) ^ ((r & 7) << 4);
        af[m] = *(const bf16x8*)((const char*)As + off);
      }
#pragma unroll
      for (int n = 0; n < 4; n++) {
        int r = wc * 64 + n * 16 + c;
        int off = (r * 128 + kk * 64 + g * 16) ^ ((r & 7) << 4);
        bfr[n] = *(const bf16x8*)((const char*)Bs + off);
      }
#pragma unroll
      for (int m = 0; m < 4; m++)
#pragma unroll
        for (int n = 0; n < 4; n++)
          acc[m][n] =
              __builtin_amdgcn_mfma_f32_16x16x32_bf16(af[m], bfr[n], acc[m][n], 0, 0, 0);
    }
  }

#pragma unroll
  for (int m = 0; m < 4; m++) {
#pragma unroll
    for (int n = 0; n < 4; n++) {
      int ocol = col0 + wc * 64 + n * 16 + c;
      int orow_base = row0 + wr * 64 + m * 16 + 4 * g;
      if constexpr (EPI == 0) {
        int which = ocol >> 10, rem = ocol & 1023;
        int h = rem >> 6, d = rem & 63;
#pragma unroll
        for (int r = 0; r < 4; r++) {
          int orow = orow_base + r;
          int b = orow >> 11, s = orow & 2047;
          int bh = b * HEADS + h;
          float av = acc[m][n][r];
          if (which == 0)
            ob0[((size_t)bh * SEQ + s) * HD + d] = f2b(av * 0.125f);  // fold 1/sqrt(64)
          else if (which == 1)
            ob1[((size_t)bh * SEQ + s) * HD + d] = f2b(av);
          else
            ob2[((size_t)bh * HD + d) * SEQ + s] = f2b(av);
        }
      } else if constexpr (EPI == 1) {
        float bia = bias[ocol];
#pragma unroll
        for (int r = 0; r < 4; r++) {
          int orow = orow_base + r;
          of0[(size_t)orow * N + ocol] =
              acc[m][n][r] + bia + res[(size_t)orow * N + ocol];
        }
      } else if constexpr (EPI == 2) {
        float bia = bias[ocol];
#pragma unroll
        for (int r = 0; r < 4; r++) {
          int orow = orow_base + r;
          float v = acc[m][n][r] + bia;
          ob0[(size_t)orow * N + ocol] = f2b(v > 0.f ? v : 0.f);
        }
      } else {
        float bia = bias[ocol];
#pragma unroll
        for (int r = 0; r < 4; r++) {
          int orow = orow_base + r;
          of0[(size_t)orow * N + ocol] = acc[m][n][r] + bia;
        }
      }
    }
  }
}

// ------- flash attention, swapped-operand (S^T = K Q^T), in-register softmax -------
// 4 waves x 16 q-cols each; KVBLK=64; K/V double-buffered, 1 barrier/tile.
// Lane (g = lane>>4, c = lane&15) owns q-row (qb*64 + w*16 + c):
//   S^T[key][q]: sc[m][r] = S[key=16m+4g+r][q=c]  (C/D map col=c, row=4g+r)
//   softmax fully lane-local (15 fmax chain + shfl_xor 16/32)
//   PV k-map (both operands): kappa(kk,g,j) = 32kk + 16*(j>>2) + 4g + (j&3)
//   => P fragment is lane-local (pack via v_cvt_pk_bf16_f32), V^T frags via ds_read_b64.
__global__ __launch_bounds__(256, 2) void k_attn(const u16* __restrict__ q,
                                                 const u16* __restrict__ kb,
                                                 const u16* __restrict__ vT,
                                                 u16* __restrict__ attn) {
  __shared__ u16 Ks[2][64 * 64];  // [key][d], 16B-chunk XOR-swizzled rows
  __shared__ u16 Vs[2][64 * 64];  // V^T tile [d][key], same swizzle
  const int tid = threadIdx.x, lane = tid & 63, w = tid >> 6;
  const int g = lane >> 4, c = lane & 15;
  const int blk = xcd_swz(blockIdx.x, gridDim.x);
  const int bh = blk >> 5, qb = blk & 31;
  const int b = bh >> 4, h = bh & 15;
  const u16* qh = q + (size_t)bh * SEQ * HD;
  const u16* kh = kb + (size_t)bh * SEQ * HD;
  const u16* vh = vT + (size_t)bh * HD * SEQ;
  const int qr = qb * 64 + w * 16 + c;  // this lane's q row (B-operand col c)
  bf16x8 qf0 = *(const bf16x8*)(qh + (size_t)qr * HD + 8 * g);        // d = 8g..8g+7
  bf16x8 qf1 = *(const bf16x8*)(qh + (size_t)qr * HD + 32 + 8 * g);   // d = 32+8g..

  const f32x4 z4 = {0.f, 0.f, 0.f, 0.f};
  f32x4 O[4];  // O^T[d=16m+4g+r][q=c]
#pragma unroll
  for (int m = 0; m < 4; m++) O[m] = z4;
  float mI = -3.0e38f, lI = 0.f;

  auto stage = [&](int kt, int buf) {
    const int kv0 = kt * 64;
#pragma unroll
    for (int i = 0; i < 2; i++) {
      int s = tid + (i << 8);
      int r = s >> 3, cb = s & 7;
      gload16(kh + (size_t)(kv0 + r) * HD + ((cb ^ (r & 7)) << 3),
              (char*)Ks[buf] + s * 16);
    }
#pragma unroll
    for (int i = 0; i < 2; i++) {
      int s = tid + (i << 8);
      int r = s >> 3, cb = s & 7;
      gload16(vh + (size_t)r * SEQ + kv0 + ((cb ^ (r & 7)) << 3),
              (char*)Vs[buf] + s * 16);
    }
  };

  stage(0, 0);
  __syncthreads();
  int cur = 0;
  constexpr int NT = SEQ / 64;
  for (int kt = 0; kt < NT; kt++) {
    if (kt + 1 < NT) stage(kt + 1, cur ^ 1);  // prefetch next tile (other buffer)

    // ---- S^T = K Q^T (A = K rows=keys, B = Q cols=q) ----
    const char* ksb = (const char*)Ks[cur];
    f32x4 sc[4];
    __builtin_amdgcn_s_setprio(1);
#pragma unroll
    for (int m = 0; m < 4; m++) {
      int r = 16 * m + c;
      int sw = (r & 7) << 4;
      bf16x8 kf0 = *(const bf16x8*)(ksb + ((r * 128 + g * 16) ^ sw));
      bf16x8 kf1 = *(const bf16x8*)(ksb + ((r * 128 + 64 + g * 16) ^ sw));
      f32x4 a = z4;
      a = __builtin_amdgcn_mfma_f32_16x16x32_bf16(kf0, qf0, a, 0, 0, 0);
      a = __builtin_amdgcn_mfma_f32_16x16x32_bf16(kf1, qf1, a, 0, 0, 0);
      sc[m] = a;
    }
    __builtin_amdgcn_s_setprio(0);

    // ---- online softmax, lane-local row (scale already folded into Q) ----
    float mx = sc[0][0];
#pragma unroll
    for (int m = 0; m < 4; m++)
#pragma unroll
      for (int r = 0; r < 4; r++) mx = fmaxf(mx, sc[m][r]);
    mx = fmaxf(mx, __shfl_xor(mx, 16));
    mx = fmaxf(mx, __shfl_xor(mx, 32));
    float mNew = fmaxf(mI, mx);
    float alpha = __expf(mI - mNew);
    mI = mNew;
    float p[4][4];
    float rs = 0.f;
#pragma unroll
    for (int m = 0; m < 4; m++)
#pragma unroll
      for (int r = 0; r < 4; r++) {
        p[m][r] = __expf(sc[m][r] - mNew);
        rs += p[m][r];
      }
    rs += __shfl_xor(rs, 16);
    rs += __shfl_xor(rs, 32);
    lI = lI * alpha + rs;
#pragma unroll
    for (int m = 0; m < 4; m++)
#pragma unroll
      for (int r = 0; r < 4; r++) O[m][r] *= alpha;

    // ---- pack P (lane-local): chunk kk covers m = 2kk,2kk+1 ----
    union V8w { bf16x8 v; u32 w4[4]; };
    V8w pa0, pa1;
    pa0.w4[0] = pk2(p[0][0], p[0][1]); pa0.w4[1] = pk2(p[0][2], p[0][3]);
    pa0.w4[2] = pk2(p[1][0], p[1][1]); pa0.w4[3] = pk2(p[1][2], p[1][3]);
    pa1.w4[0] = pk2(p[2][0], p[2][1]); pa1.w4[1] = pk2(p[2][2], p[2][3]);
    pa1.w4[2] = pk2(p[3][0], p[3][1]); pa1.w4[3] = pk2(p[3][2], p[3][3]);

    // ---- O^T += V^T P^T  (A = V^T rows=d, B = P cols=q) ----
    const char* vsb = (const char*)Vs[cur];
    union V8h { bf16x8 v; bf16x4 h2[2]; };
    __builtin_amdgcn_s_setprio(1);
#pragma unroll
    for (int m = 0; m < 4; m++) {
      int d = 16 * m + c;
      int s7 = d & 7;
      int rb = d * 128 + 8 * (g & 1);
      int ch = g >> 1;
      V8h v0, v1;
      v0.h2[0] = *(const bf16x4*)(vsb + rb + (((ch    ) ^ s7) << 4));
      v0.h2[1] = *(const bf16x4*)(vsb + rb + (((ch + 2) ^ s7) << 4));
      v1.h2[0] = *(const bf16x4*)(vsb + rb + (((ch + 4) ^ s7) << 4));
      v1.h2[1] = *(const bf16x4*)(vsb + rb + (((ch + 6) ^ s7) << 4));
      O[m] = __builtin_amdgcn_mfma_f32_16x16x32_bf16(v0.v, pa0.v, O[m], 0, 0, 0);
      O[m] = __builtin_amdgcn_mfma_f32_16x16x32_bf16(v1.v, pa1.v, O[m], 0, 0, 0);
    }
    __builtin_amdgcn_s_setprio(0);

    __syncthreads();  // drains vmcnt (prefetch done) + lgkm; safe to swap
    cur ^= 1;
  }

  // ---- epilogue: out[tok=qr][h*64 + d], d = 16m+4g+r ----
  float inv = 1.f / lI;
#pragma unroll
  for (int m = 0; m < 4; m++) {
    ushort4 ov = {f2b(O[m][0] * inv), f2b(O[m][1] * inv),
                  f2b(O[m][2] * inv), f2b(O[m][3] * inv)};
    int col = h * 64 + 16 * m + 4 * g;
    *(ushort4*)(attn + ((size_t)(b * SEQ + qr)) * EMB + col) = ov;
  }
}

// ---------------- LayerNorm kernels ----------------
__global__ __launch_bounds__(256) void k_ln1(const float* __restrict__ y,
                                             const float* __restrict__ gw,
                                             const float* __restrict__ bw,
                                             float* __restrict__ hf,
                                             u16* __restrict__ hb) {
  const int row = blockIdx.x, tid = threadIdx.x, lane = tid & 63, w = tid >> 6;
  const float4 v = ((const float4*)(y + (size_t)row * EMB))[tid];
  float s = v.x + v.y + v.z + v.w;
  float s2 = v.x * v.x + v.y * v.y + v.z * v.z + v.w * v.w;
#pragma unroll
  for (int m = 1; m < 64; m <<= 1) {
    s += __shfl_xor(s, m);
    s2 += __shfl_xor(s2, m);
  }
  __shared__ float rs_[4], rq_[4];
  if (lane == 0) { rs_[w] = s; rq_[w] = s2; }
  __syncthreads();
  s = rs_[0] + rs_[1] + rs_[2] + rs_[3];
  s2 = rq_[0] + rq_[1] + rq_[2] + rq_[3];
  const float mu = s * (1.f / EMB);
  const float var = s2 * (1.f / EMB) - mu * mu;
  const float rstd = rsqrtf(var + 1e-5f);
  const float4 gg = ((const float4*)gw)[tid];
  const float4 bb = ((const float4*)bw)[tid];
  float4 o;
  o.x = (v.x - mu) * rstd * gg.x + bb.x;
  o.y = (v.y - mu) * rstd * gg.y + bb.y;
  o.z = (v.z - mu) * rstd * gg.z + bb.z;
  o.w = (v.w - mu) * rstd * gg.w + bb.w;
  ((float4*)(hf + (size_t)row * EMB))[tid] = o;
  ushort4 ob = {f2b(o.x), f2b(o.y), f2b(o.z), f2b(o.w)};
  ((ushort4*)(hb + (size_t)row * EMB))[tid] = ob;
}

__global__ __launch_bounds__(256) void k_ln2(const float* __restrict__ hf,
                                             const float* __restrict__ z,
                                             const float* __restrict__ gw,
                                             const float* __restrict__ bw,
                                             float* __restrict__ outp) {
  const int row = blockIdx.x, tid = threadIdx.x, lane = tid & 63, w = tid >> 6;
  float4 v = ((const float4*)(hf + (size_t)row * EMB))[tid];
  const float4 zz = ((const float4*)(z + (size_t)row * EMB))[tid];
  v.x += zz.x; v.y += zz.y; v.z += zz.z; v.w += zz.w;
  float s = v.x + v.y + v.z + v.w;
  float s2 = v.x * v.x + v.y * v.y + v.z * v.z + v.w * v.w;
#pragma unroll
  for (int m = 1; m < 64; m <<= 1) {
    s += __shfl_xor(s, m);
    s2 += __shfl_xor(s2, m);
  }
  __shared__ float rs_[4], rq_[4];
  if (lane == 0) { rs_[w] = s; rq_[w] = s2; }
  __syncthreads();
  s = rs_[0] + rs_[1] + rs_[2] + rs_[3];
  s2 = rq_[0] + rq_[1] + rq_[2] + rq_[3];
  const float mu = s * (1.f / EMB);
  const float var = s2 * (1.f / EMB) - mu * mu;
  const float rstd = rsqrtf(var + 1e-5f);
  const float4 gg = ((const float4*)gw)[tid];
  const float4 bb = ((const float4*)bw)[tid];
  float4 o;
  o.x = (v.x - mu) * rstd * gg.x + bb.x;
  o.y = (v.y - mu) * rstd * gg.y + bb.y;
  o.z = (v.z - mu) * rstd * gg.z + bb.z;
  o.w = (v.w - mu) * rstd * gg.w + bb.w;
  ((float4*)(outp + (size_t)row * EMB))[tid] = o;
}

extern "C" void kernel_launch(void* const* d_in, const int* in_sizes, int n_in,
                              void* d_out, int out_size, void* d_ws, size_t ws_size,
                              hipStream_t stream) {
  const float* x = (const float*)d_in[0];
  const float* Wq = (const float*)d_in[1];
  const float* Wk = (const float*)d_in[2];
  const float* Wv = (const float*)d_in[3];
  const float* Wo = (const float*)d_in[4];
  const float* bo = (const float*)d_in[5];
  const float* g1 = (const float*)d_in[6];
  const float* b1 = (const float*)d_in[7];
  const float* W1 = (const float*)d_in[8];
  const float* bf1 = (const float*)d_in[9];
  const float* W2 = (const float*)d_in[10];
  const float* bf2 = (const float*)d_in[11];
  const float* g2 = (const float*)d_in[12];
  const float* b2 = (const float*)d_in[13];
  float* out = (float*)d_out;

  char* ws = (char*)d_ws;
  size_t off = 0;
  auto alloc = [&](size_t bytes) {
    char* p = ws + off;
    off += (bytes + 255) & ~(size_t)255;
    return p;
  };
  u16* xb = (u16*)alloc((size_t)NTOK * EMB * 2);
  u16* wqkvT = (u16*)alloc((size_t)3072 * 1024 * 2);
  u16* qB = (u16*)alloc((size_t)NTOK * EMB * 2);
  u16* kB = (u16*)alloc((size_t)NTOK * EMB * 2);
  u16* vTB = (u16*)alloc((size_t)NTOK * EMB * 2);
  u16* woT = (u16*)alloc((size_t)1024 * 1024 * 2);
  u16* w1T = (u16*)alloc((size_t)4096 * 1024 * 2);
  u16* w2T = (u16*)alloc((size_t)1024 * 4096 * 2);
  float* y = (float*)alloc((size_t)NTOK * EMB * 4);
  u16* ff1 = (u16*)alloc((size_t)NTOK * INNER * 2);
  // aliases over dead regions:
  u16* attn = xb;          // xb dead after QKV GEMM
  float* hf = (float*)qB;  // spans qB+kB, dead after attention
  u16* hb = vTB;           // dead after attention
  float* z = y;            // y dead after LN1

  k_cvt<<<NTOK * EMB / 4 / 256, 256, 0, stream>>>(x, xb, NTOK * EMB / 4);
  k_cvtT<<<1024, 256, 0, stream>>>(Wq, wqkvT, 1024, 1024);
  k_cvtT<<<1024, 256, 0, stream>>>(Wk, wqkvT + 1048576, 1024, 1024);
  k_cvtT<<<1024, 256, 0, stream>>>(Wv, wqkvT + 2097152, 1024, 1024);
  k_cvtT<<<1024, 256, 0, stream>>>(Wo, woT, 1024, 1024);
  k_cvtT<<<4096, 256, 0, stream>>>(W1, w1T, 1024, 4096);
  k_cvtT<<<4096, 256, 0, stream>>>(W2, w2T, 4096, 1024);
  // QKV projection (q pre-scaled by 0.125 in epilogue)
  k_gemm<0><<<(NTOK / 128) * (3072 / 128), 256, 0, stream>>>(
      xb, wqkvT, NTOK, 3072, 1024, qB, kB, vTB, nullptr, nullptr, nullptr);
  // attention
  k_attn<<<64 * 32, 256, 0, stream>>>(qB, kB, vTB, attn);
  // out proj + bias + residual
  k_gemm<1><<<(NTOK / 128) * (1024 / 128), 256, 0, stream>>>(
      attn, woT, NTOK, 1024, 1024, nullptr, nullptr, nullptr, y, bo, x);
  // LN1
  k_ln1<<<NTOK, 256, 0, stream>>>(y, g1, b1, hf, hb);
  // FFN1 + relu
  k_gemm<2><<<(NTOK / 128) * (4096 / 128), 256, 0, stream>>>(
      hb, w1T, NTOK, 4096, 1024, ff1, nullptr, nullptr, nullptr, bf1, nullptr);
  // FFN2
  k_gemm<3><<<(NTOK / 128) * (1024 / 128), 256, 0, stream>>>(
      ff1, w2T, NTOK, 1024, 4096, nullptr, nullptr, nullptr, z, bf2, nullptr);
  // LN2 -> out
  k_ln2<<<NTOK, 256, 0, stream>>>(hf, z, g2, b2, out);
}

// Round 5
// 574.088 us; speedup vs baseline: 1.1514x; 1.0043x over previous
//
#include <hip/hip_runtime.h>
#include <stdint.h>

#define DEVI __device__ __forceinline__

typedef __attribute__((ext_vector_type(8))) short bf16x8;
typedef __attribute__((ext_vector_type(4))) short bf16x4;
typedef __attribute__((ext_vector_type(4))) float f32x4;
typedef unsigned short u16;
typedef uint32_t u32;

constexpr int EMB = 1024, SEQ = 2048, NTOK = 8192;
constexpr int HEADS = 16, HD = 64, INNER = 4096;

DEVI u16 f2b(float f) {
  u32 u = __float_as_uint(f);
  return (u16)((u + 0x7FFFu + ((u >> 16) & 1u)) >> 16);
}

DEVI u32 pk2(float lo, float hi) {
  u32 r;
  asm("v_cvt_pk_bf16_f32 %0, %1, %2" : "=v"(r) : "v"(lo), "v"(hi));
  return r;
}

DEVI float exp2v(float x) {  // bare v_exp_f32 (exp2)
  float r;
  asm("v_exp_f32 %0, %1" : "=v"(r) : "v"(x));
  return r;
}

DEVI void gload16(const void* g, void* l) {
  __builtin_amdgcn_global_load_lds(
      (const __attribute__((address_space(1))) void*)g,
      (__attribute__((address_space(3))) void*)l, 16, 0, 0);
}

// bijective XCD-chunk swizzle; requires gridDim.x % 8 == 0 (all our grids are)
DEVI int xcd_swz(int bid, int nwg) { return (bid & 7) * (nwg >> 3) + (bid >> 3); }

// ---------------- elementwise fp32 -> bf16 ----------------
__global__ __launch_bounds__(256) void k_cvt(const float* __restrict__ src,
                                             u16* __restrict__ dst, int n4) {
  int i = blockIdx.x * 256 + threadIdx.x;
  if (i >= n4) return;
  float4 v = ((const float4*)src)[i];
  ushort4 o = {f2b(v.x), f2b(v.y), f2b(v.z), f2b(v.w)};
  ((ushort4*)dst)[i] = o;
}

// ------------- transpose + convert: dst[n][k] = bf16(src[k][n]) -------------
__global__ __launch_bounds__(256) void k_cvtT(const float* __restrict__ src,
                                              u16* __restrict__ dst, int K, int N) {
  __shared__ float t[32][33];
  int bk = blockIdx.x % (K >> 5), bn = blockIdx.x / (K >> 5);
  int tx = threadIdx.x & 31, ty = threadIdx.x >> 5;
#pragma unroll
  for (int i = 0; i < 4; i++)
    t[ty + i * 8][tx] = src[(size_t)(bk * 32 + ty + i * 8) * N + bn * 32 + tx];
  __syncthreads();
#pragma unroll
  for (int i = 0; i < 4; i++)
    dst[(size_t)(bn * 32 + ty + i * 8) * K + bk * 32 + tx] = f2b(t[tx][ty + i * 8]);
}

// ------- GEMM, triple-buffered counted-vmcnt pipeline (T4) -------
// C = A[M][K] * BT[N][K]^T. BM=256, BN=128, BK=64, 512 thr (8 waves, 4M x 2N),
// wave tile 64x64. LDS: 3 bufs x (A 32KB + B 16KB) = 144 KiB -> 1 block/CU.
// Loop invariant at iter t: buf[t%3]=tile t (landed), buf[(t+1)%3]=in flight,
// buf[(t+2)%3]=free (tile t-1 fully consumed before this iter's barrier).
// Steady-state wait: vmcnt(6) (= stage(t+1) still in flight). Never 0 mid-loop.
// EPI 0: QKV scatter (q*0.18034 [bh][s][d], k [bh][s][d], vT [bh][d][s])
// EPI 1: of0 = acc + bias + res (f32)   EPI 2: bf16(relu(acc+bias))   EPI 3: f32 acc+bias
template <int EPI>
__global__ __launch_bounds__(512, 2) void k_gemm3(
    const u16* __restrict__ A, const u16* __restrict__ BT, int M, int N, int K,
    u16* __restrict__ ob0, u16* __restrict__ ob1, u16* __restrict__ ob2,
    float* __restrict__ of0, const float* __restrict__ bias,
    const float* __restrict__ res) {
  __shared__ u16 LDS[3][24576];  // per buf: A rows 0..255 then B rows 0..127
  const int tid = threadIdx.x;
  const int lane = tid & 63, w = tid >> 6;
  const int wr = w >> 1, wc = w & 1;  // 4 M-waves x 2 N-waves
  const int g = lane >> 4, c = lane & 15;
  const int nbx = N >> 7;
  const int bid = xcd_swz(blockIdx.x, gridDim.x);
  const int by = bid / nbx, bx = bid % nbx;
  const int row0 = by << 8, col0 = bx << 7;
  const int NK = K >> 6;

  const f32x4 z4 = {0.f, 0.f, 0.f, 0.f};
  f32x4 acc[4][4];
#pragma unroll
  for (int m = 0; m < 4; m++)
#pragma unroll
    for (int n = 0; n < 4; n++) acc[m][n] = z4;

  auto stage = [&](int t, int buf) {
    const int k0 = t << 6;
    char* base = (char*)&LDS[buf][0];
#pragma unroll
    for (int i = 0; i < 4; i++) {  // A: 256 rows x 64k
      int s = tid + (i << 9);
      int r = s >> 3, cb = s & 7;
      gload16(A + (size_t)(row0 + r) * K + (k0 + ((cb ^ (r & 7)) << 3)),
              base + s * 16);
    }
#pragma unroll
    for (int i = 0; i < 2; i++) {  // B: 128 rows x 64k
      int s = tid + (i << 9);
      int r = s >> 3, cb = s & 7;
      gload16(BT + (size_t)(col0 + r) * K + (k0 + ((cb ^ (r & 7)) << 3)),
              base + 32768 + s * 16);
    }
  };

  stage(0, 0);
  stage(1, 1);
  for (int t = 0; t < NK; t++) {
    __builtin_amdgcn_sched_barrier(0);  // nothing crosses down into the wait
    if (t + 1 < NK)
      asm volatile("s_waitcnt vmcnt(6)" ::: "memory");  // tile t landed
    else
      asm volatile("s_waitcnt vmcnt(0)" ::: "memory");  // last tile: drain
    __builtin_amdgcn_s_barrier();  // publish tile t; all waves done with t-1
    __builtin_amdgcn_sched_barrier(0);  // nothing hoists above the barrier
    if (t + 2 < NK) stage(t + 2, (t + 2) % 3);  // into the freed buffer
    const char* Ab = (const char*)&LDS[t % 3][0];
    const char* Bb = Ab + 32768;
    __builtin_amdgcn_s_setprio(1);
#pragma unroll
    for (int kk = 0; kk < 2; kk++) {
      bf16x8 af[4], bfr[4];
#pragma unroll
      for (int m = 0; m < 4; m++) {
        int r = wr * 64 + m * 16 + c;
        int off = (r * 128 + kk * 64 + g * 16) ^ ((r & 7) << 4);
        af[m] = *(const bf16x8*)(Ab + off);
      }
#pragma unroll
      for (int n = 0; n < 4; n++) {
        int r = wc * 64 + n * 16 + c;
        int off = (r * 128 + kk * 64 + g * 16) ^ ((r & 7) << 4);
        bfr[n] = *(const bf16x8*)(Bb + off);
      }
#pragma unroll
      for (int m = 0; m < 4; m++)
#pragma unroll
        for (int n = 0; n < 4; n++)
          acc[m][n] =
              __builtin_amdgcn_mfma_f32_16x16x32_bf16(af[m], bfr[n], acc[m][n], 0, 0, 0);
    }
    __builtin_amdgcn_s_setprio(0);
  }

#pragma unroll
  for (int m = 0; m < 4; m++) {
#pragma unroll
    for (int n = 0; n < 4; n++) {
      int ocol = col0 + wc * 64 + n * 16 + c;
      int orow_base = row0 + wr * 64 + m * 16 + 4 * g;
      if constexpr (EPI == 0) {
        int which = ocol >> 10, rem = ocol & 1023;
        int h = rem >> 6, d = rem & 63;
#pragma unroll
        for (int r = 0; r < 4; r++) {
          int orow = orow_base + r;
          int b = orow >> 11, s = orow & 2047;
          int bh = b * HEADS + h;
          float av = acc[m][n][r];
          if (which == 0)  // fold 0.125 * log2(e) so softmax runs in exp2 domain
            ob0[((size_t)bh * SEQ + s) * HD + d] = f2b(av * 0.1803368801111244f);
          else if (which == 1)
            ob1[((size_t)bh * SEQ + s) * HD + d] = f2b(av);
          else
            ob2[((size_t)bh * HD + d) * SEQ + s] = f2b(av);
        }
      } else if constexpr (EPI == 1) {
        float bia = bias[ocol];
#pragma unroll
        for (int r = 0; r < 4; r++) {
          int orow = orow_base + r;
          of0[(size_t)orow * N + ocol] =
              acc[m][n][r] + bia + res[(size_t)orow * N + ocol];
        }
      } else if constexpr (EPI == 2) {
        float bia = bias[ocol];
#pragma unroll
        for (int r = 0; r < 4; r++) {
          int orow = orow_base + r;
          float v = acc[m][n][r] + bia;
          ob0[(size_t)orow * N + ocol] = f2b(v > 0.f ? v : 0.f);
        }
      } else {
        float bia = bias[ocol];
#pragma unroll
        for (int r = 0; r < 4; r++) {
          int orow = orow_base + r;
          of0[(size_t)orow * N + ocol] = acc[m][n][r] + bia;
        }
      }
    }
  }
}

// ------- flash attention, swapped-operand (S^T = K Q^T), exp2-domain softmax -------
// Q pre-scaled by 0.125*log2(e): p = exp2(s' - m') == softmax weights exactly.
// Defer-max (T13, THR=8 in log2 domain): skip O-rescale while max grows < 2^8.
__global__ __launch_bounds__(256, 4) void k_attn(const u16* __restrict__ q,
                                                 const u16* __restrict__ kb,
                                                 const u16* __restrict__ vT,
                                                 u16* __restrict__ attn) {
  __shared__ u16 Ks[2][64 * 64];  // [key][d], 16B-chunk XOR-swizzled rows
  __shared__ u16 Vs[2][64 * 64];  // V^T tile [d][key], same swizzle
  const int tid = threadIdx.x, lane = tid & 63, w = tid >> 6;
  const int g = lane >> 4, c = lane & 15;
  const int blk = xcd_swz(blockIdx.x, gridDim.x);
  const int bh = blk >> 5, qb = blk & 31;
  const int b = bh >> 4, h = bh & 15;
  const u16* qh = q + (size_t)bh * SEQ * HD;
  const u16* kh = kb + (size_t)bh * SEQ * HD;
  const u16* vh = vT + (size_t)bh * HD * SEQ;
  const int qr = qb * 64 + w * 16 + c;
  bf16x8 qf0 = *(const bf16x8*)(qh + (size_t)qr * HD + 8 * g);
  bf16x8 qf1 = *(const bf16x8*)(qh + (size_t)qr * HD + 32 + 8 * g);

  const f32x4 z4 = {0.f, 0.f, 0.f, 0.f};
  f32x4 O[4];  // O^T[d=16m+4g+r][q=c]
#pragma unroll
  for (int m = 0; m < 4; m++) O[m] = z4;
  float mI = -3.0e38f, lI = 0.f;

  auto stage = [&](int kt, int buf) {
    const int kv0 = kt * 64;
#pragma unroll
    for (int i = 0; i < 2; i++) {
      int s = tid + (i << 8);
      int r = s >> 3, cb = s & 7;
      gload16(kh + (size_t)(kv0 + r) * HD + ((cb ^ (r & 7)) << 3),
              (char*)Ks[buf] + s * 16);
    }
#pragma unroll
    for (int i = 0; i < 2; i++) {
      int s = tid + (i << 8);
      int r = s >> 3, cb = s & 7;
      gload16(vh + (size_t)r * SEQ + kv0 + ((cb ^ (r & 7)) << 3),
              (char*)Vs[buf] + s * 16);
    }
  };

  stage(0, 0);
  __syncthreads();
  int cur = 0;
  constexpr int NT = SEQ / 64;
  for (int kt = 0; kt < NT; kt++) {
    if (kt + 1 < NT) stage(kt + 1, cur ^ 1);  // prefetch next tile

    // ---- S^T = K Q^T ----
    const char* ksb = (const char*)Ks[cur];
    f32x4 sc[4];
    __builtin_amdgcn_s_setprio(1);
#pragma unroll
    for (int m = 0; m < 4; m++) {
      int r = 16 * m + c;
      int sw = (r & 7) << 4;
      bf16x8 kf0 = *(const bf16x8*)(ksb + ((r * 128 + g * 16) ^ sw));
      bf16x8 kf1 = *(const bf16x8*)(ksb + ((r * 128 + 64 + g * 16) ^ sw));
      f32x4 a = z4;
      a = __builtin_amdgcn_mfma_f32_16x16x32_bf16(kf0, qf0, a, 0, 0, 0);
      a = __builtin_amdgcn_mfma_f32_16x16x32_bf16(kf1, qf1, a, 0, 0, 0);
      sc[m] = a;
    }
    __builtin_amdgcn_s_setprio(0);

    // ---- online softmax in exp2 domain, lane-local row ----
    float mx = sc[0][0];
#pragma unroll
    for (int m = 0; m < 4; m++)
#pragma unroll
      for (int r = 0; r < 4; r++) mx = fmaxf(mx, sc[m][r]);
    mx = fmaxf(mx, __shfl_xor(mx, 16));
    mx = fmaxf(mx, __shfl_xor(mx, 32));
    if (!__all(mx - mI <= 8.f)) {  // defer-max: rescale only when needed
      float mNew = fmaxf(mI, mx);
      float alpha = exp2v(mI - mNew);
      lI *= alpha;
#pragma unroll
      for (int m = 0; m < 4; m++)
#pragma unroll
        for (int r = 0; r < 4; r++) O[m][r] *= alpha;
      mI = mNew;
    }
    float p[4][4];
    float rs = 0.f;
#pragma unroll
    for (int m = 0; m < 4; m++)
#pragma unroll
      for (int r = 0; r < 4; r++) {
        p[m][r] = exp2v(sc[m][r] - mI);  // bounded by 2^8
        rs += p[m][r];
      }
    rs += __shfl_xor(rs, 16);
    rs += __shfl_xor(rs, 32);
    lI += rs;

    // ---- pack P (lane-local) ----
    union V8w { bf16x8 v; u32 w4[4]; };
    V8w pa0, pa1;
    pa0.w4[0] = pk2(p[0][0], p[0][1]); pa0.w4[1] = pk2(p[0][2], p[0][3]);
    pa0.w4[2] = pk2(p[1][0], p[1][1]); pa0.w4[3] = pk2(p[1][2], p[1][3]);
    pa1.w4[0] = pk2(p[2][0], p[2][1]); pa1.w4[1] = pk2(p[2][2], p[2][3]);
    pa1.w4[2] = pk2(p[3][0], p[3][1]); pa1.w4[3] = pk2(p[3][2], p[3][3]);

    // ---- O^T += V^T P^T ----
    const char* vsb = (const char*)Vs[cur];
    union V8h { bf16x8 v; bf16x4 h2[2]; };
    __builtin_amdgcn_s_setprio(1);
#pragma unroll
    for (int m = 0; m < 4; m++) {
      int d = 16 * m + c;
      int s7 = d & 7;
      int rb = d * 128 + 8 * (g & 1);
      int ch = g >> 1;
      V8h v0, v1;
      v0.h2[0] = *(const bf16x4*)(vsb + rb + (((ch    ) ^ s7) << 4));
      v0.h2[1] = *(const bf16x4*)(vsb + rb + (((ch + 2) ^ s7) << 4));
      v1.h2[0] = *(const bf16x4*)(vsb + rb + (((ch + 4) ^ s7) << 4));
      v1.h2[1] = *(const bf16x4*)(vsb + rb + (((ch + 6) ^ s7) << 4));
      O[m] = __builtin_amdgcn_mfma_f32_16x16x32_bf16(v0.v, pa0.v, O[m], 0, 0, 0);
      O[m] = __builtin_amdgcn_mfma_f32_16x16x32_bf16(v1.v, pa1.v, O[m], 0, 0, 0);
    }
    __builtin_amdgcn_s_setprio(0);

    __syncthreads();  // drains vmcnt (prefetch done); safe to swap
    cur ^= 1;
  }

  float inv = 1.f / lI;
#pragma unroll
  for (int m = 0; m < 4; m++) {
    ushort4 ov = {f2b(O[m][0] * inv), f2b(O[m][1] * inv),
                  f2b(O[m][2] * inv), f2b(O[m][3] * inv)};
    int col = h * 64 + 16 * m + 4 * g;
    *(ushort4*)(attn + ((size_t)(b * SEQ + qr)) * EMB + col) = ov;
  }
}

// ---------------- LayerNorm kernels ----------------
__global__ __launch_bounds__(256) void k_ln1(const float* __restrict__ y,
                                             const float* __restrict__ gw,
                                             const float* __restrict__ bw,
                                             float* __restrict__ hf,
                                             u16* __restrict__ hb) {
  const int row = blockIdx.x, tid = threadIdx.x, lane = tid & 63, w = tid >> 6;
  const float4 v = ((const float4*)(y + (size_t)row * EMB))[tid];
  float s = v.x + v.y + v.z + v.w;
  float s2 = v.x * v.x + v.y * v.y + v.z * v.z + v.w * v.w;
#pragma unroll
  for (int m = 1; m < 64; m <<= 1) {
    s += __shfl_xor(s, m);
    s2 += __shfl_xor(s2, m);
  }
  __shared__ float rs_[4], rq_[4];
  if (lane == 0) { rs_[w] = s; rq_[w] = s2; }
  __syncthreads();
  s = rs_[0] + rs_[1] + rs_[2] + rs_[3];
  s2 = rq_[0] + rq_[1] + rq_[2] + rq_[3];
  const float mu = s * (1.f / EMB);
  const float var = s2 * (1.f / EMB) - mu * mu;
  const float rstd = rsqrtf(var + 1e-5f);
  const float4 gg = ((const float4*)gw)[tid];
  const float4 bb = ((const float4*)bw)[tid];
  float4 o;
  o.x = (v.x - mu) * rstd * gg.x + bb.x;
  o.y = (v.y - mu) * rstd * gg.y + bb.y;
  o.z = (v.z - mu) * rstd * gg.z + bb.z;
  o.w = (v.w - mu) * rstd * gg.w + bb.w;
  ((float4*)(hf + (size_t)row * EMB))[tid] = o;
  ushort4 ob = {f2b(o.x), f2b(o.y), f2b(o.z), f2b(o.w)};
  ((ushort4*)(hb + (size_t)row * EMB))[tid] = ob;
}

__global__ __launch_bounds__(256) void k_ln2(const float* __restrict__ hf,
                                             const float* __restrict__ z,
                                             const float* __restrict__ gw,
                                             const float* __restrict__ bw,
                                             float* __restrict__ outp) {
  const int row = blockIdx.x, tid = threadIdx.x, lane = tid & 63, w = tid >> 6;
  float4 v = ((const float4*)(hf + (size_t)row * EMB))[tid];
  const float4 zz = ((const float4*)(z + (size_t)row * EMB))[tid];
  v.x += zz.x; v.y += zz.y; v.z += zz.z; v.w += zz.w;
  float s = v.x + v.y + v.z + v.w;
  float s2 = v.x * v.x + v.y * v.y + v.z * v.z + v.w * v.w;
#pragma unroll
  for (int m = 1; m < 64; m <<= 1) {
    s += __shfl_xor(s, m);
    s2 += __shfl_xor(s2, m);
  }
  __shared__ float rs_[4], rq_[4];
  if (lane == 0) { rs_[w] = s; rq_[w] = s2; }
  __syncthreads();
  s = rs_[0] + rs_[1] + rs_[2] + rs_[3];
  s2 = rq_[0] + rq_[1] + rq_[2] + rq_[3];
  const float mu = s * (1.f / EMB);
  const float var = s2 * (1.f / EMB) - mu * mu;
  const float rstd = rsqrtf(var + 1e-5f);
  const float4 gg = ((const float4*)gw)[tid];
  const float4 bb = ((const float4*)bw)[tid];
  float4 o;
  o.x = (v.x - mu) * rstd * gg.x + bb.x;
  o.y = (v.y - mu) * rstd * gg.y + bb.y;
  o.z = (v.z - mu) * rstd * gg.z + bb.z;
  o.w = (v.w - mu) * rstd * gg.w + bb.w;
  ((float4*)(outp + (size_t)row * EMB))[tid] = o;
}

extern "C" void kernel_launch(void* const* d_in, const int* in_sizes, int n_in,
                              void* d_out, int out_size, void* d_ws, size_t ws_size,
                              hipStream_t stream) {
  const float* x = (const float*)d_in[0];
  const float* Wq = (const float*)d_in[1];
  const float* Wk = (const float*)d_in[2];
  const float* Wv = (const float*)d_in[3];
  const float* Wo = (const float*)d_in[4];
  const float* bo = (const float*)d_in[5];
  const float* g1 = (const float*)d_in[6];
  const float* b1 = (const float*)d_in[7];
  const float* W1 = (const float*)d_in[8];
  const float* bf1 = (const float*)d_in[9];
  const float* W2 = (const float*)d_in[10];
  const float* bf2 = (const float*)d_in[11];
  const float* g2 = (const float*)d_in[12];
  const float* b2 = (const float*)d_in[13];
  float* out = (float*)d_out;

  char* ws = (char*)d_ws;
  size_t off = 0;
  auto alloc = [&](size_t bytes) {
    char* p = ws + off;
    off += (bytes + 255) & ~(size_t)255;
    return p;
  };
  u16* xb = (u16*)alloc((size_t)NTOK * EMB * 2);
  u16* wqkvT = (u16*)alloc((size_t)3072 * 1024 * 2);
  u16* qB = (u16*)alloc((size_t)NTOK * EMB * 2);
  u16* kB = (u16*)alloc((size_t)NTOK * EMB * 2);
  u16* vTB = (u16*)alloc((size_t)NTOK * EMB * 2);
  u16* woT = (u16*)alloc((size_t)1024 * 1024 * 2);
  u16* w1T = (u16*)alloc((size_t)4096 * 1024 * 2);
  u16* w2T = (u16*)alloc((size_t)1024 * 4096 * 2);
  float* y = (float*)alloc((size_t)NTOK * EMB * 4);
  u16* ff1 = (u16*)alloc((size_t)NTOK * INNER * 2);
  // aliases over dead regions:
  u16* attn = xb;          // xb dead after QKV GEMM
  float* hf = (float*)qB;  // spans qB+kB, dead after attention
  u16* hb = vTB;           // dead after attention
  float* z = y;            // y dead after LN1

  k_cvt<<<NTOK * EMB / 4 / 256, 256, 0, stream>>>(x, xb, NTOK * EMB / 4);
  k_cvtT<<<1024, 256, 0, stream>>>(Wq, wqkvT, 1024, 1024);
  k_cvtT<<<1024, 256, 0, stream>>>(Wk, wqkvT + 1048576, 1024, 1024);
  k_cvtT<<<1024, 256, 0, stream>>>(Wv, wqkvT + 2097152, 1024, 1024);
  k_cvtT<<<1024, 256, 0, stream>>>(Wo, woT, 1024, 1024);
  k_cvtT<<<4096, 256, 0, stream>>>(W1, w1T, 1024, 4096);
  k_cvtT<<<4096, 256, 0, stream>>>(W2, w2T, 4096, 1024);
  // QKV projection (q pre-scaled by 0.125*log2e in epilogue)
  k_gemm3<0><<<(NTOK / 256) * (3072 / 128), 512, 0, stream>>>(
      xb, wqkvT, NTOK, 3072, 1024, qB, kB, vTB, nullptr, nullptr, nullptr);
  // attention
  k_attn<<<64 * 32, 256, 0, stream>>>(qB, kB, vTB, attn);
  // out proj + bias + residual
  k_gemm3<1><<<(NTOK / 256) * (1024 / 128), 512, 0, stream>>>(
      attn, woT, NTOK, 1024, 1024, nullptr, nullptr, nullptr, y, bo, x);
  // LN1
  k_ln1<<<NTOK, 256, 0, stream>>>(y, g1, b1, hf, hb);
  // FFN1 + relu
  k_gemm3<2><<<(NTOK / 256) * (4096 / 128), 512, 0, stream>>>(
      hb, w1T, NTOK, 4096, 1024, ff1, nullptr, nullptr, nullptr, bf1, nullptr);
  // FFN2
  k_gemm3<3><<<(NTOK / 256) * (1024 / 128), 512, 0, stream>>>(
      ff1, w2T, NTOK, 1024, 4096, nullptr, nullptr, nullptr, z, bf2, nullptr);
  // LN2 -> out
  k_ln2<<<NTOK, 256, 0, stream>>>(hf, z, g2, b2, out);
}

// Round 6
// 538.574 us; speedup vs baseline: 1.2273x; 1.0659x over previous
//
#include <hip/hip_runtime.h>
#include <stdint.h>

#define DEVI __device__ __forceinline__

typedef __attribute__((ext_vector_type(8))) short bf16x8;
typedef __attribute__((ext_vector_type(4))) float f32x4;
typedef unsigned short u16;
typedef uint32_t u32;

constexpr int EMB = 1024, SEQ = 2048, NTOK = 8192;
constexpr int HEADS = 16, HD = 64, INNER = 4096;

DEVI u16 f2b(float f) {
  u32 u = __float_as_uint(f);
  return (u16)((u + 0x7FFFu + ((u >> 16) & 1u)) >> 16);
}

DEVI u32 pk2(float lo, float hi) {
  u32 r;
  asm("v_cvt_pk_bf16_f32 %0, %1, %2" : "=v"(r) : "v"(lo), "v"(hi));
  return r;
}

DEVI float exp2v(float x) {
  float r;
  asm("v_exp_f32 %0, %1" : "=v"(r) : "v"(x));
  return r;
}

DEVI void gload16(const void* g, void* l) {
  __builtin_amdgcn_global_load_lds(
      (const __attribute__((address_space(1))) void*)g,
      (__attribute__((address_space(3))) void*)l, 16, 0, 0);
}

DEVI int xcd_swz(int bid, int nwg) { return (bid & 7) * (nwg >> 3) + (bid >> 3); }

// key k in [0,64) -> permuted position p so lane-group g's PV b128s are contiguous
DEVI int vperm(int k) {
  int g = (k >> 2) & 3, j = k & 3, s2 = k >> 4;
  return ((s2 >> 1) << 5) + (g << 3) + ((s2 & 1) << 2) + j;
}

// ---------------- elementwise fp32 -> bf16 ----------------
__global__ __launch_bounds__(256) void k_cvt(const float* __restrict__ src,
                                             u16* __restrict__ dst, int n4) {
  int i = blockIdx.x * 256 + threadIdx.x;
  if (i >= n4) return;
  float4 v = ((const float4*)src)[i];
  ushort4 o = {f2b(v.x), f2b(v.y), f2b(v.z), f2b(v.w)};
  ((ushort4*)dst)[i] = o;
}

// ------------- transpose + convert: dst[n][k] = bf16(src[k][n]) -------------
__global__ __launch_bounds__(256) void k_cvtT(const float* __restrict__ src,
                                              u16* __restrict__ dst, int K, int N) {
  __shared__ float t[32][33];
  int bk = blockIdx.x % (K >> 5), bn = blockIdx.x / (K >> 5);
  int tx = threadIdx.x & 31, ty = threadIdx.x >> 5;
#pragma unroll
  for (int i = 0; i < 4; i++)
    t[ty + i * 8][tx] = src[(size_t)(bk * 32 + ty + i * 8) * N + bn * 32 + tx];
  __syncthreads();
#pragma unroll
  for (int i = 0; i < 4; i++)
    dst[(size_t)(bn * 32 + ty + i * 8) * K + bk * 32 + tx] = f2b(t[tx][ty + i * 8]);
}

// ------- GEMM, 2-phase-per-K-tile interleave + 3-slot rotation + counted vmcnt ----
// C = A[M][K] * BT[N][K]^T. BM=256, BN=128, BK=64, 512 thr (8 waves, 4M x 2N),
// wave tile 64x64. LDS: 3 slots x (A 32KB + B 16KB) = 144 KiB.
// Slot rotation: tile t lives in slot t%3; stage(t+2) issued during tile t's
// phases targets the slot last read at tile t-1 (race-free by construction).
// vmcnt(6) once per tile (end ph1) leaves tile t+1's 6 loads in flight.
// EPI 0: QKV scatter (q*0.18034 [bh][s][d], k [bh][s][d], vT [bh][d][perm(s)])
// EPI 1: f32 acc+bias+res   EPI 2: bf16(relu(acc+bias))   EPI 3: f32 acc+bias
template <int EPI>
__global__ __launch_bounds__(512, 2) void k_gemm8(
    const u16* __restrict__ A, const u16* __restrict__ BT, int M, int N, int K,
    u16* __restrict__ ob0, u16* __restrict__ ob1, u16* __restrict__ ob2,
    float* __restrict__ of0, const float* __restrict__ bias,
    const float* __restrict__ res) {
  __shared__ u16 LDS[3][24576];  // per slot: A rows 0..255 (32KB) then B rows 0..127
  const int tid = threadIdx.x;
  const int lane = tid & 63, w = tid >> 6;
  const int wr = w >> 1, wc = w & 1;  // 4 M-waves x 2 N-waves, wave-tile 64x64
  const int g = lane >> 4, c = lane & 15;
  const int nbx = N >> 7;
  const int bid = xcd_swz(blockIdx.x, gridDim.x);
  const int by = bid / nbx, bx = bid % nbx;
  const int row0 = by << 8, col0 = bx << 7;
  const int NK = K >> 6;

  const f32x4 z4 = {0.f, 0.f, 0.f, 0.f};
  f32x4 acc[4][4];
#pragma unroll
  for (int m = 0; m < 4; m++)
#pragma unroll
    for (int n = 0; n < 4; n++) acc[m][n] = z4;

  auto stageA = [&](int t) {  // 4 loads/thread
    const int k0 = t << 6;
    char* base = (char*)&LDS[t % 3][0];
#pragma unroll
    for (int i = 0; i < 4; i++) {
      int s = tid + (i << 9);
      int r = s >> 3, cb = s & 7;
      gload16(A + (size_t)(row0 + r) * K + (k0 + ((cb ^ (r & 7)) << 3)),
              base + s * 16);
    }
  };
  auto stageB = [&](int t) {  // 2 loads/thread
    const int k0 = t << 6;
    char* base = (char*)&LDS[t % 3][0] + 32768;
#pragma unroll
    for (int i = 0; i < 2; i++) {
      int s = tid + (i << 9);
      int r = s >> 3, cb = s & 7;
      gload16(BT + (size_t)(col0 + r) * K + (k0 + ((cb ^ (r & 7)) << 3)),
              base + s * 16);
    }
  };

  // prologue: tiles 0,1 staged; drain tile 0 (leave tile 1's 6 in flight)
  stageA(0); stageB(0);
  stageA(1); stageB(1);
  asm volatile("s_waitcnt vmcnt(6)" ::: "memory");
  __builtin_amdgcn_s_barrier();

  for (int t = 0; t < NK; t++) {
    const char* Ab = (const char*)&LDS[t % 3][0];
    const char* Bb = Ab + 32768;

    // ---------- phase 0: A-frags (held both phases) + B cols [0,32) ----------
    bf16x8 af[4][2], bfr[2][2];
#pragma unroll
    for (int m = 0; m < 4; m++)
#pragma unroll
      for (int kk = 0; kk < 2; kk++) {
        int r = wr * 64 + m * 16 + c;
        af[m][kk] = *(const bf16x8*)(Ab + ((r * 128 + kk * 64 + g * 16) ^ ((r & 7) << 4)));
      }
#pragma unroll
    for (int ni = 0; ni < 2; ni++)
#pragma unroll
      for (int kk = 0; kk < 2; kk++) {
        int rb = wc * 64 + ni * 16 + c;
        bfr[ni][kk] = *(const bf16x8*)(Bb + ((rb * 128 + kk * 64 + g * 16) ^ ((rb & 7) << 4)));
      }
    if (t + 2 < NK) stageA(t + 2);
    __builtin_amdgcn_sched_barrier(0);
    __builtin_amdgcn_s_barrier();
    asm volatile("s_waitcnt lgkmcnt(0)" ::: "memory");
    __builtin_amdgcn_sched_barrier(0);
    __builtin_amdgcn_s_setprio(1);
#pragma unroll
    for (int m = 0; m < 4; m++)
#pragma unroll
      for (int ni = 0; ni < 2; ni++)
#pragma unroll
        for (int kk = 0; kk < 2; kk++)
          acc[m][ni] = __builtin_amdgcn_mfma_f32_16x16x32_bf16(af[m][kk], bfr[ni][kk],
                                                               acc[m][ni], 0, 0, 0);
    __builtin_amdgcn_s_setprio(0);
    __builtin_amdgcn_sched_barrier(0);
    __builtin_amdgcn_s_barrier();

    // ---------- phase 1: B cols [32,64), reuse A-frags ----------
#pragma unroll
    for (int ni = 0; ni < 2; ni++)
#pragma unroll
      for (int kk = 0; kk < 2; kk++) {
        int rb = wc * 64 + 32 + ni * 16 + c;
        bfr[ni][kk] = *(const bf16x8*)(Bb + ((rb * 128 + kk * 64 + g * 16) ^ ((rb & 7) << 4)));
      }
    if (t + 2 < NK) stageB(t + 2);
    __builtin_amdgcn_sched_barrier(0);
    __builtin_amdgcn_s_barrier();
    asm volatile("s_waitcnt lgkmcnt(0)" ::: "memory");
    __builtin_amdgcn_sched_barrier(0);
    __builtin_amdgcn_s_setprio(1);
#pragma unroll
    for (int m = 0; m < 4; m++)
#pragma unroll
      for (int ni = 0; ni < 2; ni++)
#pragma unroll
        for (int kk = 0; kk < 2; kk++)
          acc[m][2 + ni] = __builtin_amdgcn_mfma_f32_16x16x32_bf16(af[m][kk], bfr[ni][kk],
                                                                   acc[m][2 + ni], 0, 0, 0);
    __builtin_amdgcn_s_setprio(0);
    __builtin_amdgcn_sched_barrier(0);
    // publish: tile t+1 must be fully landed for everyone after this barrier
    if (t + 2 < NK)
      asm volatile("s_waitcnt vmcnt(6)" ::: "memory");
    else if (t + 1 < NK)
      asm volatile("s_waitcnt vmcnt(0)" ::: "memory");
    __builtin_amdgcn_s_barrier();
  }

#pragma unroll
  for (int m = 0; m < 4; m++) {
#pragma unroll
    for (int n = 0; n < 4; n++) {
      int ocol = col0 + wc * 64 + n * 16 + c;
      int orow_base = row0 + wr * 64 + m * 16 + 4 * g;
      if constexpr (EPI == 0) {
        int which = ocol >> 10, rem = ocol & 1023;
        int h = rem >> 6, d = rem & 63;
        if (which == 2) {  // V^T with per-64-block key permutation, vectorized
          int b = orow_base >> 11, sl = orow_base & 2047;
          int blk = sl & ~63, k4 = sl & 63;
          int p = vperm(k4);  // k4 % 4 == 0 -> run of 4 stays contiguous
          int bh = b * HEADS + h;
          ushort4 vv = {f2b(acc[m][n][0]), f2b(acc[m][n][1]),
                        f2b(acc[m][n][2]), f2b(acc[m][n][3])};
          *(ushort4*)(ob2 + ((size_t)bh * HD + d) * SEQ + blk + p) = vv;
        } else {
#pragma unroll
          for (int r = 0; r < 4; r++) {
            int orow = orow_base + r;
            int b = orow >> 11, s = orow & 2047;
            int bh = b * HEADS + h;
            float av = acc[m][n][r];
            if (which == 0)  // fold 0.125*log2(e): softmax runs in exp2 domain
              ob0[((size_t)bh * SEQ + s) * HD + d] = f2b(av * 0.1803368801111244f);
            else
              ob1[((size_t)bh * SEQ + s) * HD + d] = f2b(av);
          }
        }
      } else if constexpr (EPI == 1) {
        float bia = bias[ocol];
#pragma unroll
        for (int r = 0; r < 4; r++) {
          int orow = orow_base + r;
          of0[(size_t)orow * N + ocol] =
              acc[m][n][r] + bia + res[(size_t)orow * N + ocol];
        }
      } else if constexpr (EPI == 2) {
        float bia = bias[ocol];
#pragma unroll
        for (int r = 0; r < 4; r++) {
          int orow = orow_base + r;
          float v = acc[m][n][r] + bia;
          ob0[(size_t)orow * N + ocol] = f2b(v > 0.f ? v : 0.f);
        }
      } else {
        float bia = bias[ocol];
#pragma unroll
        for (int r = 0; r < 4; r++) {
          int orow = orow_base + r;
          of0[(size_t)orow * N + ocol] = acc[m][n][r] + bia;
        }
      }
    }
  }
}

// ------- flash attention, swapped-operand (S^T = K Q^T), exp2-domain softmax -------
// V^T stored key-permuted (vperm) => PV reads are 2x ds_read_b128 per m in the
// conflict-free K-read pattern; P-pack slot order matches vperm exactly.
__global__ __launch_bounds__(256, 4) void k_attn(const u16* __restrict__ q,
                                                 const u16* __restrict__ kb,
                                                 const u16* __restrict__ vT,
                                                 u16* __restrict__ attn) {
  __shared__ u16 Ks[2][64 * 64];
  __shared__ u16 Vs[2][64 * 64];
  const int tid = threadIdx.x, lane = tid & 63, w = tid >> 6;
  const int g = lane >> 4, c = lane & 15;
  const int blk = xcd_swz(blockIdx.x, gridDim.x);
  const int bh = blk >> 5, qb = blk & 31;
  const int b = bh >> 4, h = bh & 15;
  const u16* qh = q + (size_t)bh * SEQ * HD;
  const u16* kh = kb + (size_t)bh * SEQ * HD;
  const u16* vh = vT + (size_t)bh * HD * SEQ;
  const int qr = qb * 64 + w * 16 + c;
  bf16x8 qf0 = *(const bf16x8*)(qh + (size_t)qr * HD + 8 * g);
  bf16x8 qf1 = *(const bf16x8*)(qh + (size_t)qr * HD + 32 + 8 * g);

  const f32x4 z4 = {0.f, 0.f, 0.f, 0.f};
  f32x4 O[4];
#pragma unroll
  for (int m = 0; m < 4; m++) O[m] = z4;
  float mI = -3.0e38f, lI = 0.f;

  auto stage = [&](int kt, int buf) {
    const int kv0 = kt * 64;
#pragma unroll
    for (int i = 0; i < 2; i++) {
      int s = tid + (i << 8);
      int r = s >> 3, cb = s & 7;
      gload16(kh + (size_t)(kv0 + r) * HD + ((cb ^ (r & 7)) << 3),
              (char*)Ks[buf] + s * 16);
    }
#pragma unroll
    for (int i = 0; i < 2; i++) {
      int s = tid + (i << 8);
      int r = s >> 3, cb = s & 7;
      gload16(vh + (size_t)r * SEQ + kv0 + ((cb ^ (r & 7)) << 3),
              (char*)Vs[buf] + s * 16);
    }
  };

  stage(0, 0);
  __syncthreads();
  int cur = 0;
  constexpr int NT = SEQ / 64;
  for (int kt = 0; kt < NT; kt++) {
    if (kt + 1 < NT) stage(kt + 1, cur ^ 1);

    // ---- S^T = K Q^T ----
    const char* ksb = (const char*)Ks[cur];
    f32x4 sc[4];
    __builtin_amdgcn_s_setprio(1);
#pragma unroll
    for (int m = 0; m < 4; m++) {
      int r = 16 * m + c;
      int sw = (r & 7) << 4;
      bf16x8 kf0 = *(const bf16x8*)(ksb + ((r * 128 + g * 16) ^ sw));
      bf16x8 kf1 = *(const bf16x8*)(ksb + ((r * 128 + 64 + g * 16) ^ sw));
      f32x4 a = z4;
      a = __builtin_amdgcn_mfma_f32_16x16x32_bf16(kf0, qf0, a, 0, 0, 0);
      a = __builtin_amdgcn_mfma_f32_16x16x32_bf16(kf1, qf1, a, 0, 0, 0);
      sc[m] = a;
    }
    __builtin_amdgcn_s_setprio(0);

    // ---- online softmax, exp2 domain, lane-local row ----
    float mx = sc[0][0];
#pragma unroll
    for (int m = 0; m < 4; m++)
#pragma unroll
      for (int r = 0; r < 4; r++) mx = fmaxf(mx, sc[m][r]);
    mx = fmaxf(mx, __shfl_xor(mx, 16));
    mx = fmaxf(mx, __shfl_xor(mx, 32));
    if (!__all(mx - mI <= 8.f)) {
      float mNew = fmaxf(mI, mx);
      float alpha = exp2v(mI - mNew);
      lI *= alpha;
#pragma unroll
      for (int m = 0; m < 4; m++)
#pragma unroll
        for (int r = 0; r < 4; r++) O[m][r] *= alpha;
      mI = mNew;
    }
    float p[4][4];
    float rs = 0.f;
#pragma unroll
    for (int m = 0; m < 4; m++)
#pragma unroll
      for (int r = 0; r < 4; r++) {
        p[m][r] = exp2v(sc[m][r] - mI);
        rs += p[m][r];
      }
    rs += __shfl_xor(rs, 16);
    rs += __shfl_xor(rs, 32);
    lI += rs;

    // ---- pack P (lane-local; slot order == vperm) ----
    union V8w { bf16x8 v; u32 w4[4]; };
    V8w pa0, pa1;
    pa0.w4[0] = pk2(p[0][0], p[0][1]); pa0.w4[1] = pk2(p[0][2], p[0][3]);
    pa0.w4[2] = pk2(p[1][0], p[1][1]); pa0.w4[3] = pk2(p[1][2], p[1][3]);
    pa1.w4[0] = pk2(p[2][0], p[2][1]); pa1.w4[1] = pk2(p[2][2], p[2][3]);
    pa1.w4[2] = pk2(p[3][0], p[3][1]); pa1.w4[3] = pk2(p[3][2], p[3][3]);

    // ---- O^T += V^T P^T : 2x b128 per m, conflict-free pattern ----
    const char* vsb = (const char*)Vs[cur];
    __builtin_amdgcn_s_setprio(1);
#pragma unroll
    for (int m = 0; m < 4; m++) {
      int d = 16 * m + c;
      int sw = (d & 7) << 4;
      bf16x8 v0 = *(const bf16x8*)(vsb + ((d * 128 + g * 16) ^ sw));
      bf16x8 v1 = *(const bf16x8*)(vsb + ((d * 128 + 64 + g * 16) ^ sw));
      O[m] = __builtin_amdgcn_mfma_f32_16x16x32_bf16(v0, pa0.v, O[m], 0, 0, 0);
      O[m] = __builtin_amdgcn_mfma_f32_16x16x32_bf16(v1, pa1.v, O[m], 0, 0, 0);
    }
    __builtin_amdgcn_s_setprio(0);

    __syncthreads();
    cur ^= 1;
  }

  float inv = 1.f / lI;
#pragma unroll
  for (int m = 0; m < 4; m++) {
    ushort4 ov = {f2b(O[m][0] * inv), f2b(O[m][1] * inv),
                  f2b(O[m][2] * inv), f2b(O[m][3] * inv)};
    int col = h * 64 + 16 * m + 4 * g;
    *(ushort4*)(attn + ((size_t)(b * SEQ + qr)) * EMB + col) = ov;
  }
}

// ---------------- LayerNorm kernels ----------------
__global__ __launch_bounds__(256) void k_ln1(const float* __restrict__ y,
                                             const float* __restrict__ gw,
                                             const float* __restrict__ bw,
                                             float* __restrict__ hf,
                                             u16* __restrict__ hb) {
  const int row = blockIdx.x, tid = threadIdx.x, lane = tid & 63, w = tid >> 6;
  const float4 v = ((const float4*)(y + (size_t)row * EMB))[tid];
  float s = v.x + v.y + v.z + v.w;
  float s2 = v.x * v.x + v.y * v.y + v.z * v.z + v.w * v.w;
#pragma unroll
  for (int m = 1; m < 64; m <<= 1) {
    s += __shfl_xor(s, m);
    s2 += __shfl_xor(s2, m);
  }
  __shared__ float rs_[4], rq_[4];
  if (lane == 0) { rs_[w] = s; rq_[w] = s2; }
  __syncthreads();
  s = rs_[0] + rs_[1] + rs_[2] + rs_[3];
  s2 = rq_[0] + rq_[1] + rq_[2] + rq_[3];
  const float mu = s * (1.f / EMB);
  const float var = s2 * (1.f / EMB) - mu * mu;
  const float rstd = rsqrtf(var + 1e-5f);
  const float4 gg = ((const float4*)gw)[tid];
  const float4 bb = ((const float4*)bw)[tid];
  float4 o;
  o.x = (v.x - mu) * rstd * gg.x + bb.x;
  o.y = (v.y - mu) * rstd * gg.y + bb.y;
  o.z = (v.z - mu) * rstd * gg.z + bb.z;
  o.w = (v.w - mu) * rstd * gg.w + bb.w;
  ((float4*)(hf + (size_t)row * EMB))[tid] = o;
  ushort4 ob = {f2b(o.x), f2b(o.y), f2b(o.z), f2b(o.w)};
  ((ushort4*)(hb + (size_t)row * EMB))[tid] = ob;
}

__global__ __launch_bounds__(256) void k_ln2(const float* __restrict__ hf,
                                             const float* __restrict__ z,
                                             const float* __restrict__ gw,
                                             const float* __restrict__ bw,
                                             float* __restrict__ outp) {
  const int row = blockIdx.x, tid = threadIdx.x, lane = tid & 63, w = tid >> 6;
  float4 v = ((const float4*)(hf + (size_t)row * EMB))[tid];
  const float4 zz = ((const float4*)(z + (size_t)row * EMB))[tid];
  v.x += zz.x; v.y += zz.y; v.z += zz.z; v.w += zz.w;
  float s = v.x + v.y + v.z + v.w;
  float s2 = v.x * v.x + v.y * v.y + v.z * v.z + v.w * v.w;
#pragma unroll
  for (int m = 1; m < 64; m <<= 1) {
    s += __shfl_xor(s, m);
    s2 += __shfl_xor(s2, m);
  }
  __shared__ float rs_[4], rq_[4];
  if (lane == 0) { rs_[w] = s; rq_[w] = s2; }
  __syncthreads();
  s = rs_[0] + rs_[1] + rs_[2] + rs_[3];
  s2 = rq_[0] + rq_[1] + rq_[2] + rq_[3];
  const float mu = s * (1.f / EMB);
  const float var = s2 * (1.f / EMB) - mu * mu;
  const float rstd = rsqrtf(var + 1e-5f);
  const float4 gg = ((const float4*)gw)[tid];
  const float4 bb = ((const float4*)bw)[tid];
  float4 o;
  o.x = (v.x - mu) * rstd * gg.x + bb.x;
  o.y = (v.y - mu) * rstd * gg.y + bb.y;
  o.z = (v.z - mu) * rstd * gg.z + bb.z;
  o.w = (v.w - mu) * rstd * gg.w + bb.w;
  ((float4*)(outp + (size_t)row * EMB))[tid] = o;
}

extern "C" void kernel_launch(void* const* d_in, const int* in_sizes, int n_in,
                              void* d_out, int out_size, void* d_ws, size_t ws_size,
                              hipStream_t stream) {
  const float* x = (const float*)d_in[0];
  const float* Wq = (const float*)d_in[1];
  const float* Wk = (const float*)d_in[2];
  const float* Wv = (const float*)d_in[3];
  const float* Wo = (const float*)d_in[4];
  const float* bo = (const float*)d_in[5];
  const float* g1 = (const float*)d_in[6];
  const float* b1 = (const float*)d_in[7];
  const float* W1 = (const float*)d_in[8];
  const float* bf1 = (const float*)d_in[9];
  const float* W2 = (const float*)d_in[10];
  const float* bf2 = (const float*)d_in[11];
  const float* g2 = (const float*)d_in[12];
  const float* b2 = (const float*)d_in[13];
  float* out = (float*)d_out;

  char* ws = (char*)d_ws;
  size_t off = 0;
  auto alloc = [&](size_t bytes) {
    char* p = ws + off;
    off += (bytes + 255) & ~(size_t)255;
    return p;
  };
  u16* xb = (u16*)alloc((size_t)NTOK * EMB * 2);
  u16* wqkvT = (u16*)alloc((size_t)3072 * 1024 * 2);
  u16* qB = (u16*)alloc((size_t)NTOK * EMB * 2);
  u16* kB = (u16*)alloc((size_t)NTOK * EMB * 2);
  u16* vTB = (u16*)alloc((size_t)NTOK * EMB * 2);
  u16* woT = (u16*)alloc((size_t)1024 * 1024 * 2);
  u16* w1T = (u16*)alloc((size_t)4096 * 1024 * 2);
  u16* w2T = (u16*)alloc((size_t)1024 * 4096 * 2);
  float* y = (float*)alloc((size_t)NTOK * EMB * 4);
  u16* ff1 = (u16*)alloc((size_t)NTOK * INNER * 2);
  // aliases over dead regions:
  u16* attn = xb;
  float* hf = (float*)qB;
  u16* hb = vTB;
  float* z = y;

  k_cvt<<<NTOK * EMB / 4 / 256, 256, 0, stream>>>(x, xb, NTOK * EMB / 4);
  k_cvtT<<<1024, 256, 0, stream>>>(Wq, wqkvT, 1024, 1024);
  k_cvtT<<<1024, 256, 0, stream>>>(Wk, wqkvT + 1048576, 1024, 1024);
  k_cvtT<<<1024, 256, 0, stream>>>(Wv, wqkvT + 2097152, 1024, 1024);
  k_cvtT<<<1024, 256, 0, stream>>>(Wo, woT, 1024, 1024);
  k_cvtT<<<4096, 256, 0, stream>>>(W1, w1T, 1024, 4096);
  k_cvtT<<<4096, 256, 0, stream>>>(W2, w2T, 4096, 1024);
  // QKV projection (q pre-scaled by 0.125*log2e; V stored key-permuted)
  k_gemm8<0><<<(NTOK / 256) * (3072 / 128), 512, 0, stream>>>(
      xb, wqkvT, NTOK, 3072, 1024, qB, kB, vTB, nullptr, nullptr, nullptr);
  // attention
  k_attn<<<64 * 32, 256, 0, stream>>>(qB, kB, vTB, attn);
  // out proj + bias + residual
  k_gemm8<1><<<(NTOK / 256) * (1024 / 128), 512, 0, stream>>>(
      attn, woT, NTOK, 1024, 1024, nullptr, nullptr, nullptr, y, bo, x);
  // LN1
  k_ln1<<<NTOK, 256, 0, stream>>>(y, g1, b1, hf, hb);
  // FFN1 + relu
  k_gemm8<2><<<(NTOK / 256) * (4096 / 128), 512, 0, stream>>>(
      hb, w1T, NTOK, 4096, 1024, ff1, nullptr, nullptr, nullptr, bf1, nullptr);
  // FFN2
  k_gemm8<3><<<(NTOK / 256) * (1024 / 128), 512, 0, stream>>>(
      ff1, w2T, NTOK, 1024, 4096, nullptr, nullptr, nullptr, z, bf2, nullptr);
  // LN2 -> out
  k_ln2<<<NTOK, 256, 0, stream>>>(hf, z, g2, b2, out);
}

// Round 7
// 534.657 us; speedup vs baseline: 1.2363x; 1.0073x over previous
//
#include <hip/hip_runtime.h>
#include <stdint.h>

#define DEVI __device__ __forceinline__

typedef __attribute__((ext_vector_type(8))) short bf16x8;
typedef __attribute__((ext_vector_type(4))) float f32x4;
typedef unsigned short u16;
typedef uint32_t u32;

constexpr int EMB = 1024, SEQ = 2048, NTOK = 8192;
constexpr int HEADS = 16, HD = 64, INNER = 4096;

DEVI u16 f2b(float f) {
  u32 u = __float_as_uint(f);
  return (u16)((u + 0x7FFFu + ((u >> 16) & 1u)) >> 16);
}

DEVI u32 pk2(float lo, float hi) {
  u32 r;
  asm("v_cvt_pk_bf16_f32 %0, %1, %2" : "=v"(r) : "v"(lo), "v"(hi));
  return r;
}

DEVI float exp2v(float x) {
  float r;
  asm("v_exp_f32 %0, %1" : "=v"(r) : "v"(x));
  return r;
}

DEVI void gload16(const void* g, void* l) {
  __builtin_amdgcn_global_load_lds(
      (const __attribute__((address_space(1))) void*)g,
      (__attribute__((address_space(3))) void*)l, 16, 0, 0);
}

DEVI int xcd_swz(int bid, int nwg) { return (bid & 7) * (nwg >> 3) + (bid >> 3); }

// key k in [0,64) -> permuted position p so lane-group g's PV b128s are contiguous
DEVI int vperm(int k) {
  int g = (k >> 2) & 3, j = k & 3, s2 = k >> 4;
  return ((s2 >> 1) << 5) + (g << 3) + ((s2 & 1) << 2) + j;
}

// ---------------- elementwise fp32 -> bf16 ----------------
__global__ __launch_bounds__(256) void k_cvt(const float* __restrict__ src,
                                             u16* __restrict__ dst, int n4) {
  int i = blockIdx.x * 256 + threadIdx.x;
  if (i >= n4) return;
  float4 v = ((const float4*)src)[i];
  ushort4 o = {f2b(v.x), f2b(v.y), f2b(v.z), f2b(v.w)};
  ((ushort4*)dst)[i] = o;
}

// ------------- transpose + convert: dst[n][k] = bf16(src[k][n]) -------------
__global__ __launch_bounds__(256) void k_cvtT(const float* __restrict__ src,
                                              u16* __restrict__ dst, int K, int N) {
  __shared__ float t[32][33];
  int bk = blockIdx.x % (K >> 5), bn = blockIdx.x / (K >> 5);
  int tx = threadIdx.x & 31, ty = threadIdx.x >> 5;
#pragma unroll
  for (int i = 0; i < 4; i++)
    t[ty + i * 8][tx] = src[(size_t)(bk * 32 + ty + i * 8) * N + bn * 32 + tx];
  __syncthreads();
#pragma unroll
  for (int i = 0; i < 4; i++)
    dst[(size_t)(bn * 32 + ty + i * 8) * K + bk * 32 + tx] = f2b(t[tx][ty + i * 8]);
}

// ===== 256x256 4-phase GEMM (m201-class). A 3-slot + B 2-slot = 160KiB LDS. =====
// 8 waves 2M x 4N, wave tile 128x64, acc[8][4]. Quadrants per K-tile:
// ph0:(m0-3,n0-1) ph1:(m0-3,n2-3) ph2:(m4-7,n0-1) ph3:(m4-7,n2-3), 16 MFMA each.
// Stage map: tile t stages B(t+1) halves in ph0/ph1, A(t+2) halves in ph2/ph3.
// Boundary wait vmcnt(4) (A(t+2) left in flight). Never 0 mid-loop.
template <int EPI>
__global__ __launch_bounds__(512, 2) void k_g256(
    const u16* __restrict__ A, const u16* __restrict__ BT, int M, int N, int K,
    u16* __restrict__ ob0, u16* __restrict__ ob1, u16* __restrict__ ob2,
    float* __restrict__ of0, const float* __restrict__ bias,
    const float* __restrict__ res) {
  __shared__ u16 LDS[81920];  // A slots @ 0/32K/64K bytes; B slots @ 96K/128K
  const int tid = threadIdx.x;
  const int lane = tid & 63, w = tid >> 6;
  const int wr = w >> 2, wc = w & 3;  // 2M x 4N
  const int g = lane >> 4, c = lane & 15;
  const int nbx = N >> 8;
  const int bid = xcd_swz(blockIdx.x, gridDim.x);
  const int by = bid / nbx, bx = bid % nbx;
  const int row0 = by << 8, col0 = bx << 8;
  const int NK = K >> 6;

  const f32x4 z4 = {0.f, 0.f, 0.f, 0.f};
  f32x4 acc[8][4];
#pragma unroll
  for (int m = 0; m < 8; m++)
#pragma unroll
    for (int n = 0; n < 4; n++) acc[m][n] = z4;

  auto stA = [&](int t, int h) {  // half h of A(t): 2 loads/thread
    const int k0 = t << 6;
    char* base = (char*)LDS + (t % 3) * 32768 + h * 16384;
#pragma unroll
    for (int i = 0; i < 2; i++) {
      int s = tid + (i << 9);
      int r = (h << 7) + (s >> 3), cb = s & 7;
      gload16(A + (size_t)(row0 + r) * K + (k0 + ((cb ^ (r & 7)) << 3)),
              base + s * 16);
    }
  };
  auto stB = [&](int t, int h) {
    const int k0 = t << 6;
    char* base = (char*)LDS + 98304 + (t & 1) * 32768 + h * 16384;
#pragma unroll
    for (int i = 0; i < 2; i++) {
      int s = tid + (i << 9);
      int r = (h << 7) + (s >> 3), cb = s & 7;
      gload16(BT + (size_t)(col0 + r) * K + (k0 + ((cb ^ (r & 7)) << 3)),
              base + s * 16);
    }
  };
  auto rdA = [&](const char* Ab, int row, int kk) {
    return *(const bf16x8*)(Ab + ((row * 128 + kk * 64 + g * 16) ^ ((row & 7) << 4)));
  };

  // prologue: A(0), B(0), A(1) staged; wait A(0)+B(0) landed (A(1) in flight)
  stA(0, 0); stA(0, 1);
  stB(0, 0); stB(0, 1);
  stA(1, 0); stA(1, 1);
  asm volatile("s_waitcnt vmcnt(4)" ::: "memory");
  __builtin_amdgcn_s_barrier();
  __builtin_amdgcn_sched_barrier(0);

  for (int t = 0; t < NK; t++) {
    const char* Ab = (const char*)LDS + (t % 3) * 32768;
    const char* Bb = (const char*)LDS + 98304 + (t & 1) * 32768;
    bf16x8 af[4][2], b0[2][2], b1[2][2];

    // ---------- ph0: ds A(m0-3) 8 + B(n0-1) 4; stage B0(t+1) ----------
#pragma unroll
    for (int m = 0; m < 4; m++)
#pragma unroll
      for (int kk = 0; kk < 2; kk++) af[m][kk] = rdA(Ab, wr * 128 + m * 16 + c, kk);
#pragma unroll
    for (int n = 0; n < 2; n++)
#pragma unroll
      for (int kk = 0; kk < 2; kk++) b0[n][kk] = rdA(Bb, wc * 64 + n * 16 + c, kk);
    if (t + 1 < NK) stB(t + 1, 0);
    asm volatile("s_waitcnt lgkmcnt(8)" ::: "memory");  // throttle (12 issued)
    __builtin_amdgcn_sched_barrier(0);
    __builtin_amdgcn_s_barrier();
    asm volatile("s_waitcnt lgkmcnt(0)" ::: "memory");
    __builtin_amdgcn_sched_barrier(0);
    __builtin_amdgcn_s_setprio(1);
#pragma unroll
    for (int m = 0; m < 4; m++)
#pragma unroll
      for (int n = 0; n < 2; n++)
#pragma unroll
        for (int kk = 0; kk < 2; kk++)
          acc[m][n] = __builtin_amdgcn_mfma_f32_16x16x32_bf16(af[m][kk], b0[n][kk],
                                                              acc[m][n], 0, 0, 0);
    __builtin_amdgcn_s_setprio(0);
    __builtin_amdgcn_sched_barrier(0);
    __builtin_amdgcn_s_barrier();

    // ---------- ph1: ds B(n2-3) 4; stage B1(t+1) ----------
#pragma unroll
    for (int n = 0; n < 2; n++)
#pragma unroll
      for (int kk = 0; kk < 2; kk++)
        b1[n][kk] = rdA(Bb, wc * 64 + 32 + n * 16 + c, kk);
    if (t + 1 < NK) stB(t + 1, 1);
    __builtin_amdgcn_sched_barrier(0);
    __builtin_amdgcn_s_barrier();
    asm volatile("s_waitcnt lgkmcnt(0)" ::: "memory");
    __builtin_amdgcn_sched_barrier(0);
    __builtin_amdgcn_s_setprio(1);
#pragma unroll
    for (int m = 0; m < 4; m++)
#pragma unroll
      for (int n = 0; n < 2; n++)
#pragma unroll
        for (int kk = 0; kk < 2; kk++)
          acc[m][2 + n] = __builtin_amdgcn_mfma_f32_16x16x32_bf16(af[m][kk], b1[n][kk],
                                                                  acc[m][2 + n], 0, 0, 0);
    __builtin_amdgcn_s_setprio(0);
    __builtin_amdgcn_sched_barrier(0);
    __builtin_amdgcn_s_barrier();

    // ---------- ph2: ds A(m4-7) 8; stage A0(t+2); reuse b0 ----------
#pragma unroll
    for (int m = 0; m < 4; m++)
#pragma unroll
      for (int kk = 0; kk < 2; kk++)
        af[m][kk] = rdA(Ab, wr * 128 + 64 + m * 16 + c, kk);
    if (t + 2 < NK) stA(t + 2, 0);
    __builtin_amdgcn_sched_barrier(0);
    __builtin_amdgcn_s_barrier();
    asm volatile("s_waitcnt lgkmcnt(0)" ::: "memory");
    __builtin_amdgcn_sched_barrier(0);
    __builtin_amdgcn_s_setprio(1);
#pragma unroll
    for (int m = 0; m < 4; m++)
#pragma unroll
      for (int n = 0; n < 2; n++)
#pragma unroll
        for (int kk = 0; kk < 2; kk++)
          acc[4 + m][n] = __builtin_amdgcn_mfma_f32_16x16x32_bf16(af[m][kk], b0[n][kk],
                                                                  acc[4 + m][n], 0, 0, 0);
    __builtin_amdgcn_s_setprio(0);
    __builtin_amdgcn_sched_barrier(0);
    __builtin_amdgcn_s_barrier();

    // ---------- ph3: no ds; stage A1(t+2); reuse af+b1; boundary wait ----------
    if (t + 2 < NK) stA(t + 2, 1);
    __builtin_amdgcn_sched_barrier(0);
    __builtin_amdgcn_s_barrier();
    __builtin_amdgcn_s_setprio(1);
#pragma unroll
    for (int m = 0; m < 4; m++)
#pragma unroll
      for (int n = 0; n < 2; n++)
#pragma unroll
        for (int kk = 0; kk < 2; kk++)
          acc[4 + m][2 + n] = __builtin_amdgcn_mfma_f32_16x16x32_bf16(
              af[m][kk], b1[n][kk], acc[4 + m][2 + n], 0, 0, 0);
    __builtin_amdgcn_s_setprio(0);
    __builtin_amdgcn_sched_barrier(0);
    if (t + 2 < NK)
      asm volatile("s_waitcnt vmcnt(4)" ::: "memory");  // A(t+1),B(t+1) landed
    else if (t + 1 < NK)
      asm volatile("s_waitcnt vmcnt(0)" ::: "memory");  // drain last B
    __builtin_amdgcn_s_barrier();
    __builtin_amdgcn_sched_barrier(0);
  }

#pragma unroll
  for (int m = 0; m < 8; m++) {
#pragma unroll
    for (int n = 0; n < 4; n++) {
      int ocol = col0 + wc * 64 + n * 16 + c;
      int orow_base = row0 + wr * 128 + m * 16 + 4 * g;
      if constexpr (EPI == 0) {
        int which = ocol >> 10, rem = ocol & 1023;
        int h = rem >> 6, d = rem & 63;
        if (which == 2) {
          int b = orow_base >> 11, sl = orow_base & 2047;
          int blk = sl & ~63, k4 = sl & 63;
          int p = vperm(k4);
          int bh = b * HEADS + h;
          ushort4 vv = {f2b(acc[m][n][0]), f2b(acc[m][n][1]),
                        f2b(acc[m][n][2]), f2b(acc[m][n][3])};
          *(ushort4*)(ob2 + ((size_t)bh * HD + d) * SEQ + blk + p) = vv;
        } else {
#pragma unroll
          for (int r = 0; r < 4; r++) {
            int orow = orow_base + r;
            int b = orow >> 11, s = orow & 2047;
            int bh = b * HEADS + h;
            float av = acc[m][n][r];
            if (which == 0)
              ob0[((size_t)bh * SEQ + s) * HD + d] = f2b(av * 0.1803368801111244f);
            else
              ob1[((size_t)bh * SEQ + s) * HD + d] = f2b(av);
          }
        }
      } else if constexpr (EPI == 2) {
        float bia = bias[ocol];
#pragma unroll
        for (int r = 0; r < 4; r++) {
          int orow = orow_base + r;
          float v = acc[m][n][r] + bia;
          ob0[(size_t)orow * N + ocol] = f2b(v > 0.f ? v : 0.f);
        }
      } else {
        float bia = bias[ocol];
#pragma unroll
        for (int r = 0; r < 4; r++) {
          int orow = orow_base + r;
          float v = acc[m][n][r] + bia;
          if constexpr (EPI == 1)
            of0[(size_t)orow * N + ocol] = v + res[(size_t)orow * N + ocol];
          else
            of0[(size_t)orow * N + ocol] = v;
        }
      }
    }
  }
}

// ------- GEMM 256x128 2-phase (verified round-6 kernel) for N=1024 GEMMs -------
template <int EPI>
__global__ __launch_bounds__(512, 2) void k_gemm8(
    const u16* __restrict__ A, const u16* __restrict__ BT, int M, int N, int K,
    u16* __restrict__ ob0, u16* __restrict__ ob1, u16* __restrict__ ob2,
    float* __restrict__ of0, const float* __restrict__ bias,
    const float* __restrict__ res) {
  __shared__ u16 LDS[3][24576];
  const int tid = threadIdx.x;
  const int lane = tid & 63, w = tid >> 6;
  const int wr = w >> 1, wc = w & 1;
  const int g = lane >> 4, c = lane & 15;
  const int nbx = N >> 7;
  const int bid = xcd_swz(blockIdx.x, gridDim.x);
  const int by = bid / nbx, bx = bid % nbx;
  const int row0 = by << 8, col0 = bx << 7;
  const int NK = K >> 6;

  const f32x4 z4 = {0.f, 0.f, 0.f, 0.f};
  f32x4 acc[4][4];
#pragma unroll
  for (int m = 0; m < 4; m++)
#pragma unroll
    for (int n = 0; n < 4; n++) acc[m][n] = z4;

  auto stageA = [&](int t) {
    const int k0 = t << 6;
    char* base = (char*)&LDS[t % 3][0];
#pragma unroll
    for (int i = 0; i < 4; i++) {
      int s = tid + (i << 9);
      int r = s >> 3, cb = s & 7;
      gload16(A + (size_t)(row0 + r) * K + (k0 + ((cb ^ (r & 7)) << 3)),
              base + s * 16);
    }
  };
  auto stageB = [&](int t) {
    const int k0 = t << 6;
    char* base = (char*)&LDS[t % 3][0] + 32768;
#pragma unroll
    for (int i = 0; i < 2; i++) {
      int s = tid + (i << 9);
      int r = s >> 3, cb = s & 7;
      gload16(BT + (size_t)(col0 + r) * K + (k0 + ((cb ^ (r & 7)) << 3)),
              base + s * 16);
    }
  };

  stageA(0); stageB(0);
  stageA(1); stageB(1);
  asm volatile("s_waitcnt vmcnt(6)" ::: "memory");
  __builtin_amdgcn_s_barrier();

  for (int t = 0; t < NK; t++) {
    const char* Ab = (const char*)&LDS[t % 3][0];
    const char* Bb = Ab + 32768;

    bf16x8 af[4][2], bfr[2][2];
#pragma unroll
    for (int m = 0; m < 4; m++)
#pragma unroll
      for (int kk = 0; kk < 2; kk++) {
        int r = wr * 64 + m * 16 + c;
        af[m][kk] = *(const bf16x8*)(Ab + ((r * 128 + kk * 64 + g * 16) ^ ((r & 7) << 4)));
      }
#pragma unroll
    for (int ni = 0; ni < 2; ni++)
#pragma unroll
      for (int kk = 0; kk < 2; kk++) {
        int rb = wc * 64 + ni * 16 + c;
        bfr[ni][kk] = *(const bf16x8*)(Bb + ((rb * 128 + kk * 64 + g * 16) ^ ((rb & 7) << 4)));
      }
    if (t + 2 < NK) stageA(t + 2);
    __builtin_amdgcn_sched_barrier(0);
    __builtin_amdgcn_s_barrier();
    asm volatile("s_waitcnt lgkmcnt(0)" ::: "memory");
    __builtin_amdgcn_sched_barrier(0);
    __builtin_amdgcn_s_setprio(1);
#pragma unroll
    for (int m = 0; m < 4; m++)
#pragma unroll
      for (int ni = 0; ni < 2; ni++)
#pragma unroll
        for (int kk = 0; kk < 2; kk++)
          acc[m][ni] = __builtin_amdgcn_mfma_f32_16x16x32_bf16(af[m][kk], bfr[ni][kk],
                                                               acc[m][ni], 0, 0, 0);
    __builtin_amdgcn_s_setprio(0);
    __builtin_amdgcn_sched_barrier(0);
    __builtin_amdgcn_s_barrier();

#pragma unroll
    for (int ni = 0; ni < 2; ni++)
#pragma unroll
      for (int kk = 0; kk < 2; kk++) {
        int rb = wc * 64 + 32 + ni * 16 + c;
        bfr[ni][kk] = *(const bf16x8*)(Bb + ((rb * 128 + kk * 64 + g * 16) ^ ((rb & 7) << 4)));
      }
    if (t + 2 < NK) stageB(t + 2);
    __builtin_amdgcn_sched_barrier(0);
    __builtin_amdgcn_s_barrier();
    asm volatile("s_waitcnt lgkmcnt(0)" ::: "memory");
    __builtin_amdgcn_sched_barrier(0);
    __builtin_amdgcn_s_setprio(1);
#pragma unroll
    for (int m = 0; m < 4; m++)
#pragma unroll
      for (int ni = 0; ni < 2; ni++)
#pragma unroll
        for (int kk = 0; kk < 2; kk++)
          acc[m][2 + ni] = __builtin_amdgcn_mfma_f32_16x16x32_bf16(af[m][kk], bfr[ni][kk],
                                                                   acc[m][2 + ni], 0, 0, 0);
    __builtin_amdgcn_s_setprio(0);
    __builtin_amdgcn_sched_barrier(0);
    if (t + 2 < NK)
      asm volatile("s_waitcnt vmcnt(6)" ::: "memory");
    else if (t + 1 < NK)
      asm volatile("s_waitcnt vmcnt(0)" ::: "memory");
    __builtin_amdgcn_s_barrier();
  }

#pragma unroll
  for (int m = 0; m < 4; m++) {
#pragma unroll
    for (int n = 0; n < 4; n++) {
      int ocol = col0 + wc * 64 + n * 16 + c;
      int orow_base = row0 + wr * 64 + m * 16 + 4 * g;
      if constexpr (EPI == 1) {
        float bia = bias[ocol];
#pragma unroll
        for (int r = 0; r < 4; r++) {
          int orow = orow_base + r;
          of0[(size_t)orow * N + ocol] =
              acc[m][n][r] + bia + res[(size_t)orow * N + ocol];
        }
      } else {
        float bia = bias[ocol];
#pragma unroll
        for (int r = 0; r < 4; r++) {
          int orow = orow_base + r;
          of0[(size_t)orow * N + ocol] = acc[m][n][r] + bia;
        }
      }
    }
  }
}

// ------- flash attention (round-6 verified: vperm PV, exp2 softmax, defer-max) ----
__global__ __launch_bounds__(256, 4) void k_attn(const u16* __restrict__ q,
                                                 const u16* __restrict__ kb,
                                                 const u16* __restrict__ vT,
                                                 u16* __restrict__ attn) {
  __shared__ u16 Ks[2][64 * 64];
  __shared__ u16 Vs[2][64 * 64];
  const int tid = threadIdx.x, lane = tid & 63, w = tid >> 6;
  const int g = lane >> 4, c = lane & 15;
  const int blk = xcd_swz(blockIdx.x, gridDim.x);
  const int bh = blk >> 5, qb = blk & 31;
  const int b = bh >> 4, h = bh & 15;
  const u16* qh = q + (size_t)bh * SEQ * HD;
  const u16* kh = kb + (size_t)bh * SEQ * HD;
  const u16* vh = vT + (size_t)bh * HD * SEQ;
  const int qr = qb * 64 + w * 16 + c;
  bf16x8 qf0 = *(const bf16x8*)(qh + (size_t)qr * HD + 8 * g);
  bf16x8 qf1 = *(const bf16x8*)(qh + (size_t)qr * HD + 32 + 8 * g);

  const f32x4 z4 = {0.f, 0.f, 0.f, 0.f};
  f32x4 O[4];
#pragma unroll
  for (int m = 0; m < 4; m++) O[m] = z4;
  float mI = -3.0e38f, lI = 0.f;

  auto stage = [&](int kt, int buf) {
    const int kv0 = kt * 64;
#pragma unroll
    for (int i = 0; i < 2; i++) {
      int s = tid + (i << 8);
      int r = s >> 3, cb = s & 7;
      gload16(kh + (size_t)(kv0 + r) * HD + ((cb ^ (r & 7)) << 3),
              (char*)Ks[buf] + s * 16);
    }
#pragma unroll
    for (int i = 0; i < 2; i++) {
      int s = tid + (i << 8);
      int r = s >> 3, cb = s & 7;
      gload16(vh + (size_t)r * SEQ + kv0 + ((cb ^ (r & 7)) << 3),
              (char*)Vs[buf] + s * 16);
    }
  };

  stage(0, 0);
  __syncthreads();
  int cur = 0;
  constexpr int NT = SEQ / 64;
  for (int kt = 0; kt < NT; kt++) {
    if (kt + 1 < NT) stage(kt + 1, cur ^ 1);

    const char* ksb = (const char*)Ks[cur];
    f32x4 sc[4];
    __builtin_amdgcn_s_setprio(1);
#pragma unroll
    for (int m = 0; m < 4; m++) {
      int r = 16 * m + c;
      int sw = (r & 7) << 4;
      bf16x8 kf0 = *(const bf16x8*)(ksb + ((r * 128 + g * 16) ^ sw));
      bf16x8 kf1 = *(const bf16x8*)(ksb + ((r * 128 + 64 + g * 16) ^ sw));
      f32x4 a = z4;
      a = __builtin_amdgcn_mfma_f32_16x16x32_bf16(kf0, qf0, a, 0, 0, 0);
      a = __builtin_amdgcn_mfma_f32_16x16x32_bf16(kf1, qf1, a, 0, 0, 0);
      sc[m] = a;
    }
    __builtin_amdgcn_s_setprio(0);

    float mx = sc[0][0];
#pragma unroll
    for (int m = 0; m < 4; m++)
#pragma unroll
      for (int r = 0; r < 4; r++) mx = fmaxf(mx, sc[m][r]);
    mx = fmaxf(mx, __shfl_xor(mx, 16));
    mx = fmaxf(mx, __shfl_xor(mx, 32));
    if (!__all(mx - mI <= 8.f)) {
      float mNew = fmaxf(mI, mx);
      float alpha = exp2v(mI - mNew);
      lI *= alpha;
#pragma unroll
      for (int m = 0; m < 4; m++)
#pragma unroll
        for (int r = 0; r < 4; r++) O[m][r] *= alpha;
      mI = mNew;
    }
    float p[4][4];
    float rs = 0.f;
#pragma unroll
    for (int m = 0; m < 4; m++)
#pragma unroll
      for (int r = 0; r < 4; r++) {
        p[m][r] = exp2v(sc[m][r] - mI);
        rs += p[m][r];
      }
    rs += __shfl_xor(rs, 16);
    rs += __shfl_xor(rs, 32);
    lI += rs;

    union V8w { bf16x8 v; u32 w4[4]; };
    V8w pa0, pa1;
    pa0.w4[0] = pk2(p[0][0], p[0][1]); pa0.w4[1] = pk2(p[0][2], p[0][3]);
    pa0.w4[2] = pk2(p[1][0], p[1][1]); pa0.w4[3] = pk2(p[1][2], p[1][3]);
    pa1.w4[0] = pk2(p[2][0], p[2][1]); pa1.w4[1] = pk2(p[2][2], p[2][3]);
    pa1.w4[2] = pk2(p[3][0], p[3][1]); pa1.w4[3] = pk2(p[3][2], p[3][3]);

    const char* vsb = (const char*)Vs[cur];
    __builtin_amdgcn_s_setprio(1);
#pragma unroll
    for (int m = 0; m < 4; m++) {
      int d = 16 * m + c;
      int sw = (d & 7) << 4;
      bf16x8 v0 = *(const bf16x8*)(vsb + ((d * 128 + g * 16) ^ sw));
      bf16x8 v1 = *(const bf16x8*)(vsb + ((d * 128 + 64 + g * 16) ^ sw));
      O[m] = __builtin_amdgcn_mfma_f32_16x16x32_bf16(v0, pa0.v, O[m], 0, 0, 0);
      O[m] = __builtin_amdgcn_mfma_f32_16x16x32_bf16(v1, pa1.v, O[m], 0, 0, 0);
    }
    __builtin_amdgcn_s_setprio(0);

    __syncthreads();
    cur ^= 1;
  }

  float inv = 1.f / lI;
#pragma unroll
  for (int m = 0; m < 4; m++) {
    ushort4 ov = {f2b(O[m][0] * inv), f2b(O[m][1] * inv),
                  f2b(O[m][2] * inv), f2b(O[m][3] * inv)};
    int col = h * 64 + 16 * m + 4 * g;
    *(ushort4*)(attn + ((size_t)(b * SEQ + qr)) * EMB + col) = ov;
  }
}

// ---------------- LayerNorm kernels ----------------
__global__ __launch_bounds__(256) void k_ln1(const float* __restrict__ y,
                                             const float* __restrict__ gw,
                                             const float* __restrict__ bw,
                                             float* __restrict__ hf,
                                             u16* __restrict__ hb) {
  const int row = blockIdx.x, tid = threadIdx.x, lane = tid & 63, w = tid >> 6;
  const float4 v = ((const float4*)(y + (size_t)row * EMB))[tid];
  float s = v.x + v.y + v.z + v.w;
  float s2 = v.x * v.x + v.y * v.y + v.z * v.z + v.w * v.w;
#pragma unroll
  for (int m = 1; m < 64; m <<= 1) {
    s += __shfl_xor(s, m);
    s2 += __shfl_xor(s2, m);
  }
  __shared__ float rs_[4], rq_[4];
  if (lane == 0) { rs_[w] = s; rq_[w] = s2; }
  __syncthreads();
  s = rs_[0] + rs_[1] + rs_[2] + rs_[3];
  s2 = rq_[0] + rq_[1] + rq_[2] + rq_[3];
  const float mu = s * (1.f / EMB);
  const float var = s2 * (1.f / EMB) - mu * mu;
  const float rstd = rsqrtf(var + 1e-5f);
  const float4 gg = ((const float4*)gw)[tid];
  const float4 bb = ((const float4*)bw)[tid];
  float4 o;
  o.x = (v.x - mu) * rstd * gg.x + bb.x;
  o.y = (v.y - mu) * rstd * gg.y + bb.y;
  o.z = (v.z - mu) * rstd * gg.z + bb.z;
  o.w = (v.w - mu) * rstd * gg.w + bb.w;
  ((float4*)(hf + (size_t)row * EMB))[tid] = o;
  ushort4 ob = {f2b(o.x), f2b(o.y), f2b(o.z), f2b(o.w)};
  ((ushort4*)(hb + (size_t)row * EMB))[tid] = ob;
}

__global__ __launch_bounds__(256) void k_ln2(const float* __restrict__ hf,
                                             const float* __restrict__ z,
                                             const float* __restrict__ gw,
                                             const float* __restrict__ bw,
                                             float* __restrict__ outp) {
  const int row = blockIdx.x, tid = threadIdx.x, lane = tid & 63, w = tid >> 6;
  float4 v = ((const float4*)(hf + (size_t)row * EMB))[tid];
  const float4 zz = ((const float4*)(z + (size_t)row * EMB))[tid];
  v.x += zz.x; v.y += zz.y; v.z += zz.z; v.w += zz.w;
  float s = v.x + v.y + v.z + v.w;
  float s2 = v.x * v.x + v.y * v.y + v.z * v.z + v.w * v.w;
#pragma unroll
  for (int m = 1; m < 64; m <<= 1) {
    s += __shfl_xor(s, m);
    s2 += __shfl_xor(s2, m);
  }
  __shared__ float rs_[4], rq_[4];
  if (lane == 0) { rs_[w] = s; rq_[w] = s2; }
  __syncthreads();
  s = rs_[0] + rs_[1] + rs_[2] + rs_[3];
  s2 = rq_[0] + rq_[1] + rq_[2] + rq_[3];
  const float mu = s * (1.f / EMB);
  const float var = s2 * (1.f / EMB) - mu * mu;
  const float rstd = rsqrtf(var + 1e-5f);
  const float4 gg = ((const float4*)gw)[tid];
  const float4 bb = ((const float4*)bw)[tid];
  float4 o;
  o.x = (v.x - mu) * rstd * gg.x + bb.x;
  o.y = (v.y - mu) * rstd * gg.y + bb.y;
  o.z = (v.z - mu) * rstd * gg.z + bb.z;
  o.w = (v.w - mu) * rstd * gg.w + bb.w;
  ((float4*)(outp + (size_t)row * EMB))[tid] = o;
}

extern "C" void kernel_launch(void* const* d_in, const int* in_sizes, int n_in,
                              void* d_out, int out_size, void* d_ws, size_t ws_size,
                              hipStream_t stream) {
  const float* x = (const float*)d_in[0];
  const float* Wq = (const float*)d_in[1];
  const float* Wk = (const float*)d_in[2];
  const float* Wv = (const float*)d_in[3];
  const float* Wo = (const float*)d_in[4];
  const float* bo = (const float*)d_in[5];
  const float* g1 = (const float*)d_in[6];
  const float* b1 = (const float*)d_in[7];
  const float* W1 = (const float*)d_in[8];
  const float* bf1 = (const float*)d_in[9];
  const float* W2 = (const float*)d_in[10];
  const float* bf2 = (const float*)d_in[11];
  const float* g2 = (const float*)d_in[12];
  const float* b2 = (const float*)d_in[13];
  float* out = (float*)d_out;

  char* ws = (char*)d_ws;
  size_t off = 0;
  auto alloc = [&](size_t bytes) {
    char* p = ws + off;
    off += (bytes + 255) & ~(size_t)255;
    return p;
  };
  u16* xb = (u16*)alloc((size_t)NTOK * EMB * 2);
  u16* wqkvT = (u16*)alloc((size_t)3072 * 1024 * 2);
  u16* qB = (u16*)alloc((size_t)NTOK * EMB * 2);
  u16* kB = (u16*)alloc((size_t)NTOK * EMB * 2);
  u16* vTB = (u16*)alloc((size_t)NTOK * EMB * 2);
  u16* woT = (u16*)alloc((size_t)1024 * 1024 * 2);
  u16* w1T = (u16*)alloc((size_t)4096 * 1024 * 2);
  u16* w2T = (u16*)alloc((size_t)1024 * 4096 * 2);
  float* y = (float*)alloc((size_t)NTOK * EMB * 4);
  u16* ff1 = (u16*)alloc((size_t)NTOK * INNER * 2);
  u16* attn = xb;
  float* hf = (float*)qB;
  u16* hb = vTB;
  float* z = y;

  k_cvt<<<NTOK * EMB / 4 / 256, 256, 0, stream>>>(x, xb, NTOK * EMB / 4);
  k_cvtT<<<1024, 256, 0, stream>>>(Wq, wqkvT, 1024, 1024);
  k_cvtT<<<1024, 256, 0, stream>>>(Wk, wqkvT + 1048576, 1024, 1024);
  k_cvtT<<<1024, 256, 0, stream>>>(Wv, wqkvT + 2097152, 1024, 1024);
  k_cvtT<<<1024, 256, 0, stream>>>(Wo, woT, 1024, 1024);
  k_cvtT<<<4096, 256, 0, stream>>>(W1, w1T, 1024, 4096);
  k_cvtT<<<4096, 256, 0, stream>>>(W2, w2T, 4096, 1024);
  // QKV projection: 256x256 4-phase kernel (384 blocks)
  k_g256<0><<<(NTOK / 256) * (3072 / 256), 512, 0, stream>>>(
      xb, wqkvT, NTOK, 3072, 1024, qB, kB, vTB, nullptr, nullptr, nullptr);
  // attention
  k_attn<<<64 * 32, 256, 0, stream>>>(qB, kB, vTB, attn);
  // out proj + bias + residual: 256x128 kernel (256 blocks)
  k_gemm8<1><<<(NTOK / 256) * (1024 / 128), 512, 0, stream>>>(
      attn, woT, NTOK, 1024, 1024, nullptr, nullptr, nullptr, y, bo, x);
  // LN1
  k_ln1<<<NTOK, 256, 0, stream>>>(y, g1, b1, hf, hb);
  // FFN1 + relu: 256x256 4-phase kernel (512 blocks)
  k_g256<2><<<(NTOK / 256) * (4096 / 256), 512, 0, stream>>>(
      hb, w1T, NTOK, 4096, 1024, ff1, nullptr, nullptr, nullptr, bf1, nullptr);
  // FFN2: 256x128 kernel (256 blocks)
  k_gemm8<3><<<(NTOK / 256) * (1024 / 128), 512, 0, stream>>>(
      ff1, w2T, NTOK, 1024, 4096, nullptr, nullptr, nullptr, z, bf2, nullptr);
  // LN2 -> out
  k_ln2<<<NTOK, 256, 0, stream>>>(hf, z, g2, b2, out);
}

// Round 8
// 509.761 us; speedup vs baseline: 1.2967x; 1.0488x over previous
//
#include <hip/hip_runtime.h>
#include <stdint.h>

#define DEVI __device__ __forceinline__

typedef __attribute__((ext_vector_type(8))) short bf16x8;
typedef __attribute__((ext_vector_type(4))) float f32x4;
typedef unsigned short u16;
typedef uint32_t u32;

constexpr int EMB = 1024, SEQ = 2048, NTOK = 8192;
constexpr int HEADS = 16, HD = 64, INNER = 4096;

DEVI u16 f2b(float f) {
  u32 u = __float_as_uint(f);
  return (u16)((u + 0x7FFFu + ((u >> 16) & 1u)) >> 16);
}
DEVI float b2f(u16 h) { return __uint_as_float(((u32)h) << 16); }

DEVI u32 pk2(float lo, float hi) {
  u32 r;
  asm("v_cvt_pk_bf16_f32 %0, %1, %2" : "=v"(r) : "v"(lo), "v"(hi));
  return r;
}

DEVI float exp2v(float x) {
  float r;
  asm("v_exp_f32 %0, %1" : "=v"(r) : "v"(x));
  return r;
}

DEVI void gload16(const void* g, void* l) {
  __builtin_amdgcn_global_load_lds(
      (const __attribute__((address_space(1))) void*)g,
      (__attribute__((address_space(3))) void*)l, 16, 0, 0);
}

DEVI int xcd_swz(int bid, int nwg) { return (bid & 7) * (nwg >> 3) + (bid >> 3); }

// key k in [0,64) -> permuted position p so lane-group g's PV b128s are contiguous
DEVI int vperm(int k) {
  int g = (k >> 2) & 3, j = k & 3, s2 = k >> 4;
  return ((s2 >> 1) << 5) + (g << 3) + ((s2 & 1) << 2) + j;
}

// ---- fused prep: x->bf16 (blocks 0..8191) + 6 weight transposes (12288 blocks) ----
__global__ __launch_bounds__(256) void k_prep(
    const float* __restrict__ x, const float* __restrict__ Wq,
    const float* __restrict__ Wk, const float* __restrict__ Wv,
    const float* __restrict__ Wo, const float* __restrict__ W1,
    const float* __restrict__ W2, u16* __restrict__ xb, u16* __restrict__ wqkvT,
    u16* __restrict__ woT, u16* __restrict__ w1T, u16* __restrict__ w2T) {
  __shared__ float t[32][33];
  int b = blockIdx.x;
  if (b < 8192) {
    int i = b * 256 + threadIdx.x;
    float4 v = ((const float4*)x)[i];
    ushort4 o = {f2b(v.x), f2b(v.y), f2b(v.z), f2b(v.w)};
    ((ushort4*)xb)[i] = o;
    return;
  }
  b -= 8192;
  const float* src;
  u16* dst;
  int K, N;
  if (b < 4096) {
    int m = b >> 10;
    b &= 1023;
    K = 1024; N = 1024;
    src = (m == 0) ? Wq : (m == 1) ? Wk : (m == 2) ? Wv : Wo;
    dst = (m == 0) ? wqkvT : (m == 1) ? wqkvT + 1048576
        : (m == 2) ? wqkvT + 2097152 : woT;
  } else if (b < 8192) {
    b -= 4096; src = W1; dst = w1T; K = 1024; N = 4096;
  } else {
    b -= 8192; src = W2; dst = w2T; K = 4096; N = 1024;
  }
  int bk = b % (K >> 5), bn = b / (K >> 5);
  int tx = threadIdx.x & 31, ty = threadIdx.x >> 5;
#pragma unroll
  for (int i = 0; i < 4; i++)
    t[ty + i * 8][tx] = src[(size_t)(bk * 32 + ty + i * 8) * N + bn * 32 + tx];
  __syncthreads();
#pragma unroll
  for (int i = 0; i < 4; i++)
    dst[(size_t)(bn * 32 + ty + i * 8) * K + bk * 32 + tx] = f2b(t[tx][ty + i * 8]);
}

// ===== 256x256 4-phase GEMM. A 3-slot + B 2-slot = 160KiB LDS. Minimal fencing. ====
template <int EPI>
__global__ __launch_bounds__(512, 2) void k_g256(
    const u16* __restrict__ A, const u16* __restrict__ BT, int M, int N, int K,
    u16* __restrict__ ob0, u16* __restrict__ ob1, u16* __restrict__ ob2,
    float* __restrict__ of0, const float* __restrict__ bias,
    const float* __restrict__ res) {
  __shared__ u16 LDS[81920];
  const int tid = threadIdx.x;
  const int lane = tid & 63, w = tid >> 6;
  const int wr = w >> 2, wc = w & 3;  // 2M x 4N
  const int g = lane >> 4, c = lane & 15;
  const int nbx = N >> 8;
  const int bid = xcd_swz(blockIdx.x, gridDim.x);
  const int by = bid / nbx, bx = bid % nbx;
  const int row0 = by << 8, col0 = bx << 8;
  const int NK = K >> 6;

  const f32x4 z4 = {0.f, 0.f, 0.f, 0.f};
  f32x4 acc[8][4];
#pragma unroll
  for (int m = 0; m < 8; m++)
#pragma unroll
    for (int n = 0; n < 4; n++) acc[m][n] = z4;

  auto stA = [&](int t, int h) {
    const int k0 = t << 6;
    char* base = (char*)LDS + (t % 3) * 32768 + h * 16384;
#pragma unroll
    for (int i = 0; i < 2; i++) {
      int s = tid + (i << 9);
      int r = (h << 7) + (s >> 3), cb = s & 7;
      gload16(A + (size_t)(row0 + r) * K + (k0 + ((cb ^ (r & 7)) << 3)),
              base + s * 16);
    }
  };
  auto stB = [&](int t, int h) {
    const int k0 = t << 6;
    char* base = (char*)LDS + 98304 + (t & 1) * 32768 + h * 16384;
#pragma unroll
    for (int i = 0; i < 2; i++) {
      int s = tid + (i << 9);
      int r = (h << 7) + (s >> 3), cb = s & 7;
      gload16(BT + (size_t)(col0 + r) * K + (k0 + ((cb ^ (r & 7)) << 3)),
              base + s * 16);
    }
  };
  auto rdA = [&](const char* Ab, int row, int kk) {
    return *(const bf16x8*)(Ab + ((row * 128 + kk * 64 + g * 16) ^ ((row & 7) << 4)));
  };

  stA(0, 0); stA(0, 1);
  stB(0, 0); stB(0, 1);
  stA(1, 0); stA(1, 1);
  asm volatile("s_waitcnt vmcnt(4)" ::: "memory");
  __builtin_amdgcn_s_barrier();

  for (int t = 0; t < NK; t++) {
    const char* Ab = (const char*)LDS + (t % 3) * 32768;
    const char* Bb = (const char*)LDS + 98304 + (t & 1) * 32768;
    bf16x8 af[4][2], b0[2][2], b1[2][2];

    // ph0: ds A(m0-3)+B(n0-1); stage B0(t+1)
#pragma unroll
    for (int m = 0; m < 4; m++)
#pragma unroll
      for (int kk = 0; kk < 2; kk++) af[m][kk] = rdA(Ab, wr * 128 + m * 16 + c, kk);
#pragma unroll
    for (int n = 0; n < 2; n++)
#pragma unroll
      for (int kk = 0; kk < 2; kk++) b0[n][kk] = rdA(Bb, wc * 64 + n * 16 + c, kk);
    if (t + 1 < NK) stB(t + 1, 0);
    __builtin_amdgcn_s_barrier();
    asm volatile("s_waitcnt lgkmcnt(0)" ::: "memory");
    __builtin_amdgcn_sched_barrier(0);
    __builtin_amdgcn_s_setprio(1);
#pragma unroll
    for (int m = 0; m < 4; m++)
#pragma unroll
      for (int n = 0; n < 2; n++)
#pragma unroll
        for (int kk = 0; kk < 2; kk++)
          acc[m][n] = __builtin_amdgcn_mfma_f32_16x16x32_bf16(af[m][kk], b0[n][kk],
                                                              acc[m][n], 0, 0, 0);
    __builtin_amdgcn_s_setprio(0);
    __builtin_amdgcn_s_barrier();

    // ph1: ds B(n2-3); stage B1(t+1)
#pragma unroll
    for (int n = 0; n < 2; n++)
#pragma unroll
      for (int kk = 0; kk < 2; kk++)
        b1[n][kk] = rdA(Bb, wc * 64 + 32 + n * 16 + c, kk);
    if (t + 1 < NK) stB(t + 1, 1);
    __builtin_amdgcn_s_barrier();
    asm volatile("s_waitcnt lgkmcnt(0)" ::: "memory");
    __builtin_amdgcn_sched_barrier(0);
    __builtin_amdgcn_s_setprio(1);
#pragma unroll
    for (int m = 0; m < 4; m++)
#pragma unroll
      for (int n = 0; n < 2; n++)
#pragma unroll
        for (int kk = 0; kk < 2; kk++)
          acc[m][2 + n] = __builtin_amdgcn_mfma_f32_16x16x32_bf16(af[m][kk], b1[n][kk],
                                                                  acc[m][2 + n], 0, 0, 0);
    __builtin_amdgcn_s_setprio(0);
    __builtin_amdgcn_s_barrier();

    // ph2: ds A(m4-7); stage A0(t+2); reuse b0
#pragma unroll
    for (int m = 0; m < 4; m++)
#pragma unroll
      for (int kk = 0; kk < 2; kk++)
        af[m][kk] = rdA(Ab, wr * 128 + 64 + m * 16 + c, kk);
    if (t + 2 < NK) stA(t + 2, 0);
    __builtin_amdgcn_s_barrier();
    asm volatile("s_waitcnt lgkmcnt(0)" ::: "memory");
    __builtin_amdgcn_sched_barrier(0);
    __builtin_amdgcn_s_setprio(1);
#pragma unroll
    for (int m = 0; m < 4; m++)
#pragma unroll
      for (int n = 0; n < 2; n++)
#pragma unroll
        for (int kk = 0; kk < 2; kk++)
          acc[4 + m][n] = __builtin_amdgcn_mfma_f32_16x16x32_bf16(af[m][kk], b0[n][kk],
                                                                  acc[4 + m][n], 0, 0, 0);
    __builtin_amdgcn_s_setprio(0);
    __builtin_amdgcn_s_barrier();

    // ph3: stage A1(t+2); reuse af+b1; boundary wait vmcnt(4)
    if (t + 2 < NK) stA(t + 2, 1);
    __builtin_amdgcn_s_barrier();
    __builtin_amdgcn_s_setprio(1);
#pragma unroll
    for (int m = 0; m < 4; m++)
#pragma unroll
      for (int n = 0; n < 2; n++)
#pragma unroll
        for (int kk = 0; kk < 2; kk++)
          acc[4 + m][2 + n] = __builtin_amdgcn_mfma_f32_16x16x32_bf16(
              af[m][kk], b1[n][kk], acc[4 + m][2 + n], 0, 0, 0);
    __builtin_amdgcn_s_setprio(0);
    if (t + 2 < NK)
      asm volatile("s_waitcnt vmcnt(4)" ::: "memory");
    else if (t + 1 < NK)
      asm volatile("s_waitcnt vmcnt(0)" ::: "memory");
    __builtin_amdgcn_s_barrier();
  }

#pragma unroll
  for (int m = 0; m < 8; m++) {
#pragma unroll
    for (int n = 0; n < 4; n++) {
      int ocol = col0 + wc * 64 + n * 16 + c;
      int orow_base = row0 + wr * 128 + m * 16 + 4 * g;
      if constexpr (EPI == 0) {
        int which = ocol >> 10, rem = ocol & 1023;
        int h = rem >> 6, d = rem & 63;
        if (which == 2) {
          int b = orow_base >> 11, sl = orow_base & 2047;
          int blk = sl & ~63, k4 = sl & 63;
          int p = vperm(k4);
          int bh = b * HEADS + h;
          ushort4 vv = {f2b(acc[m][n][0]), f2b(acc[m][n][1]),
                        f2b(acc[m][n][2]), f2b(acc[m][n][3])};
          *(ushort4*)(ob2 + ((size_t)bh * HD + d) * SEQ + blk + p) = vv;
        } else {
#pragma unroll
          for (int r = 0; r < 4; r++) {
            int orow = orow_base + r;
            int b = orow >> 11, s = orow & 2047;
            int bh = b * HEADS + h;
            float av = acc[m][n][r];
            if (which == 0)
              ob0[((size_t)bh * SEQ + s) * HD + d] = f2b(av * 0.1803368801111244f);
            else
              ob1[((size_t)bh * SEQ + s) * HD + d] = f2b(av);
          }
        }
      } else {  // EPI == 2: bf16(relu(acc+bias))
        float bia = bias[ocol];
#pragma unroll
        for (int r = 0; r < 4; r++) {
          int orow = orow_base + r;
          float v = acc[m][n][r] + bia;
          ob0[(size_t)orow * N + ocol] = f2b(v > 0.f ? v : 0.f);
        }
      }
    }
  }
}

// ------- GEMM 256x128 2-phase (verified) for N=1024 GEMMs -------
// EPI 1: ob0 = bf16(acc + bias + res)   EPI 3: of0 = acc + bias (f32)
template <int EPI>
__global__ __launch_bounds__(512, 2) void k_gemm8(
    const u16* __restrict__ A, const u16* __restrict__ BT, int M, int N, int K,
    u16* __restrict__ ob0, float* __restrict__ of0, const float* __restrict__ bias,
    const float* __restrict__ res) {
  __shared__ u16 LDS[3][24576];
  const int tid = threadIdx.x;
  const int lane = tid & 63, w = tid >> 6;
  const int wr = w >> 1, wc = w & 1;
  const int g = lane >> 4, c = lane & 15;
  const int nbx = N >> 7;
  const int bid = xcd_swz(blockIdx.x, gridDim.x);
  const int by = bid / nbx, bx = bid % nbx;
  const int row0 = by << 8, col0 = bx << 7;
  const int NK = K >> 6;

  const f32x4 z4 = {0.f, 0.f, 0.f, 0.f};
  f32x4 acc[4][4];
#pragma unroll
  for (int m = 0; m < 4; m++)
#pragma unroll
    for (int n = 0; n < 4; n++) acc[m][n] = z4;

  auto stageA = [&](int t) {
    const int k0 = t << 6;
    char* base = (char*)&LDS[t % 3][0];
#pragma unroll
    for (int i = 0; i < 4; i++) {
      int s = tid + (i << 9);
      int r = s >> 3, cb = s & 7;
      gload16(A + (size_t)(row0 + r) * K + (k0 + ((cb ^ (r & 7)) << 3)),
              base + s * 16);
    }
  };
  auto stageB = [&](int t) {
    const int k0 = t << 6;
    char* base = (char*)&LDS[t % 3][0] + 32768;
#pragma unroll
    for (int i = 0; i < 2; i++) {
      int s = tid + (i << 9);
      int r = s >> 3, cb = s & 7;
      gload16(BT + (size_t)(col0 + r) * K + (k0 + ((cb ^ (r & 7)) << 3)),
              base + s * 16);
    }
  };

  stageA(0); stageB(0);
  stageA(1); stageB(1);
  asm volatile("s_waitcnt vmcnt(6)" ::: "memory");
  __builtin_amdgcn_s_barrier();

  for (int t = 0; t < NK; t++) {
    const char* Ab = (const char*)&LDS[t % 3][0];
    const char* Bb = Ab + 32768;

    bf16x8 af[4][2], bfr[2][2];
#pragma unroll
    for (int m = 0; m < 4; m++)
#pragma unroll
      for (int kk = 0; kk < 2; kk++) {
        int r = wr * 64 + m * 16 + c;
        af[m][kk] = *(const bf16x8*)(Ab + ((r * 128 + kk * 64 + g * 16) ^ ((r & 7) << 4)));
      }
#pragma unroll
    for (int ni = 0; ni < 2; ni++)
#pragma unroll
      for (int kk = 0; kk < 2; kk++) {
        int rb = wc * 64 + ni * 16 + c;
        bfr[ni][kk] = *(const bf16x8*)(Bb + ((rb * 128 + kk * 64 + g * 16) ^ ((rb & 7) << 4)));
      }
    if (t + 2 < NK) stageA(t + 2);
    __builtin_amdgcn_sched_barrier(0);
    __builtin_amdgcn_s_barrier();
    asm volatile("s_waitcnt lgkmcnt(0)" ::: "memory");
    __builtin_amdgcn_sched_barrier(0);
    __builtin_amdgcn_s_setprio(1);
#pragma unroll
    for (int m = 0; m < 4; m++)
#pragma unroll
      for (int ni = 0; ni < 2; ni++)
#pragma unroll
        for (int kk = 0; kk < 2; kk++)
          acc[m][ni] = __builtin_amdgcn_mfma_f32_16x16x32_bf16(af[m][kk], bfr[ni][kk],
                                                               acc[m][ni], 0, 0, 0);
    __builtin_amdgcn_s_setprio(0);
    __builtin_amdgcn_sched_barrier(0);
    __builtin_amdgcn_s_barrier();

#pragma unroll
    for (int ni = 0; ni < 2; ni++)
#pragma unroll
      for (int kk = 0; kk < 2; kk++) {
        int rb = wc * 64 + 32 + ni * 16 + c;
        bfr[ni][kk] = *(const bf16x8*)(Bb + ((rb * 128 + kk * 64 + g * 16) ^ ((rb & 7) << 4)));
      }
    if (t + 2 < NK) stageB(t + 2);
    __builtin_amdgcn_sched_barrier(0);
    __builtin_amdgcn_s_barrier();
    asm volatile("s_waitcnt lgkmcnt(0)" ::: "memory");
    __builtin_amdgcn_sched_barrier(0);
    __builtin_amdgcn_s_setprio(1);
#pragma unroll
    for (int m = 0; m < 4; m++)
#pragma unroll
      for (int ni = 0; ni < 2; ni++)
#pragma unroll
        for (int kk = 0; kk < 2; kk++)
          acc[m][2 + ni] = __builtin_amdgcn_mfma_f32_16x16x32_bf16(af[m][kk], bfr[ni][kk],
                                                                   acc[m][2 + ni], 0, 0, 0);
    __builtin_amdgcn_s_setprio(0);
    __builtin_amdgcn_sched_barrier(0);
    if (t + 2 < NK)
      asm volatile("s_waitcnt vmcnt(6)" ::: "memory");
    else if (t + 1 < NK)
      asm volatile("s_waitcnt vmcnt(0)" ::: "memory");
    __builtin_amdgcn_s_barrier();
  }

#pragma unroll
  for (int m = 0; m < 4; m++) {
#pragma unroll
    for (int n = 0; n < 4; n++) {
      int ocol = col0 + wc * 64 + n * 16 + c;
      int orow_base = row0 + wr * 64 + m * 16 + 4 * g;
      float bia = bias[ocol];
#pragma unroll
      for (int r = 0; r < 4; r++) {
        int orow = orow_base + r;
        if constexpr (EPI == 1)
          ob0[(size_t)orow * N + ocol] =
              f2b(acc[m][n][r] + bia + res[(size_t)orow * N + ocol]);
        else
          of0[(size_t)orow * N + ocol] = acc[m][n][r] + bia;
      }
    }
  }
}

// ------- flash attention (vperm PV, exp2 softmax, defer-max, deferred l-reduce) ----
__global__ __launch_bounds__(256, 4) void k_attn(const u16* __restrict__ q,
                                                 const u16* __restrict__ kb,
                                                 const u16* __restrict__ vT,
                                                 u16* __restrict__ attn) {
  __shared__ u16 Ks[2][64 * 64];
  __shared__ u16 Vs[2][64 * 64];
  const int tid = threadIdx.x, lane = tid & 63, w = tid >> 6;
  const int g = lane >> 4, c = lane & 15;
  const int blk = xcd_swz(blockIdx.x, gridDim.x);
  const int bh = blk >> 5, qb = blk & 31;
  const int b = bh >> 4, h = bh & 15;
  const u16* qh = q + (size_t)bh * SEQ * HD;
  const u16* kh = kb + (size_t)bh * SEQ * HD;
  const u16* vh = vT + (size_t)bh * HD * SEQ;
  const int qr = qb * 64 + w * 16 + c;
  bf16x8 qf0 = *(const bf16x8*)(qh + (size_t)qr * HD + 8 * g);
  bf16x8 qf1 = *(const bf16x8*)(qh + (size_t)qr * HD + 32 + 8 * g);

  const f32x4 z4 = {0.f, 0.f, 0.f, 0.f};
  f32x4 O[4];
#pragma unroll
  for (int m = 0; m < 4; m++) O[m] = z4;
  float mI = -3.0e38f, lI = 0.f;  // lI is LANE-PARTIAL (16 keys); reduced at end

  auto stage = [&](int kt, int buf) {
    const int kv0 = kt * 64;
#pragma unroll
    for (int i = 0; i < 2; i++) {
      int s = tid + (i << 8);
      int r = s >> 3, cb = s & 7;
      gload16(kh + (size_t)(kv0 + r) * HD + ((cb ^ (r & 7)) << 3),
              (char*)Ks[buf] + s * 16);
    }
#pragma unroll
    for (int i = 0; i < 2; i++) {
      int s = tid + (i << 8);
      int r = s >> 3, cb = s & 7;
      gload16(vh + (size_t)r * SEQ + kv0 + ((cb ^ (r & 7)) << 3),
              (char*)Vs[buf] + s * 16);
    }
  };

  stage(0, 0);
  __syncthreads();
  int cur = 0;
  constexpr int NT = SEQ / 64;
  for (int kt = 0; kt < NT; kt++) {
    if (kt + 1 < NT) stage(kt + 1, cur ^ 1);

    const char* ksb = (const char*)Ks[cur];
    f32x4 sc[4];
    __builtin_amdgcn_s_setprio(1);
#pragma unroll
    for (int m = 0; m < 4; m++) {
      int r = 16 * m + c;
      int sw = (r & 7) << 4;
      bf16x8 kf0 = *(const bf16x8*)(ksb + ((r * 128 + g * 16) ^ sw));
      bf16x8 kf1 = *(const bf16x8*)(ksb + ((r * 128 + 64 + g * 16) ^ sw));
      f32x4 a = z4;
      a = __builtin_amdgcn_mfma_f32_16x16x32_bf16(kf0, qf0, a, 0, 0, 0);
      a = __builtin_amdgcn_mfma_f32_16x16x32_bf16(kf1, qf1, a, 0, 0, 0);
      sc[m] = a;
    }
    __builtin_amdgcn_s_setprio(0);

    // max via nested triples (v_max3)
    float a0 = fmaxf(fmaxf(sc[0][0], sc[0][1]), sc[0][2]);
    float a1 = fmaxf(fmaxf(sc[0][3], sc[1][0]), sc[1][1]);
    float a2 = fmaxf(fmaxf(sc[1][2], sc[1][3]), sc[2][0]);
    float a3 = fmaxf(fmaxf(sc[2][1], sc[2][2]), sc[2][3]);
    float a4 = fmaxf(fmaxf(sc[3][0], sc[3][1]), sc[3][2]);
    float b0 = fmaxf(fmaxf(a0, a1), a2);
    float b1 = fmaxf(fmaxf(a3, a4), sc[3][3]);
    float mx = fmaxf(b0, b1);
    mx = fmaxf(mx, __shfl_xor(mx, 16));
    mx = fmaxf(mx, __shfl_xor(mx, 32));
    if (!__all(mx - mI <= 8.f)) {
      float mNew = fmaxf(mI, mx);
      float alpha = exp2v(mI - mNew);
      lI *= alpha;
#pragma unroll
      for (int m = 0; m < 4; m++)
#pragma unroll
        for (int r = 0; r < 4; r++) O[m][r] *= alpha;
      mI = mNew;
    }
    float p[4][4];
    float rs = 0.f;
#pragma unroll
    for (int m = 0; m < 4; m++)
#pragma unroll
      for (int r = 0; r < 4; r++) {
        p[m][r] = exp2v(sc[m][r] - mI);
        rs += p[m][r];
      }
    lI += rs;  // lane-partial; cross-lane reduce deferred to epilogue

    union V8w { bf16x8 v; u32 w4[4]; };
    V8w pa0, pa1;
    pa0.w4[0] = pk2(p[0][0], p[0][1]); pa0.w4[1] = pk2(p[0][2], p[0][3]);
    pa0.w4[2] = pk2(p[1][0], p[1][1]); pa0.w4[3] = pk2(p[1][2], p[1][3]);
    pa1.w4[0] = pk2(p[2][0], p[2][1]); pa1.w4[1] = pk2(p[2][2], p[2][3]);
    pa1.w4[2] = pk2(p[3][0], p[3][1]); pa1.w4[3] = pk2(p[3][2], p[3][3]);

    const char* vsb = (const char*)Vs[cur];
    __builtin_amdgcn_s_setprio(1);
#pragma unroll
    for (int m = 0; m < 4; m++) {
      int d = 16 * m + c;
      int sw = (d & 7) << 4;
      bf16x8 v0 = *(const bf16x8*)(vsb + ((d * 128 + g * 16) ^ sw));
      bf16x8 v1 = *(const bf16x8*)(vsb + ((d * 128 + 64 + g * 16) ^ sw));
      O[m] = __builtin_amdgcn_mfma_f32_16x16x32_bf16(v0, pa0.v, O[m], 0, 0, 0);
      O[m] = __builtin_amdgcn_mfma_f32_16x16x32_bf16(v1, pa1.v, O[m], 0, 0, 0);
    }
    __builtin_amdgcn_s_setprio(0);

    __syncthreads();
    cur ^= 1;
  }

  lI += __shfl_xor(lI, 16);
  lI += __shfl_xor(lI, 32);
  float inv = 1.f / lI;
#pragma unroll
  for (int m = 0; m < 4; m++) {
    ushort4 ov = {f2b(O[m][0] * inv), f2b(O[m][1] * inv),
                  f2b(O[m][2] * inv), f2b(O[m][3] * inv)};
    int col = h * 64 + 16 * m + 4 * g;
    *(ushort4*)(attn + ((size_t)(b * SEQ + qr)) * EMB + col) = ov;
  }
}

// ---------------- LayerNorm kernels (bf16 inputs on residual path) ----------------
__global__ __launch_bounds__(256) void k_ln1(const u16* __restrict__ y,
                                             const float* __restrict__ gw,
                                             const float* __restrict__ bw,
                                             u16* __restrict__ hb) {
  const int row = blockIdx.x, tid = threadIdx.x, lane = tid & 63, w = tid >> 6;
  ushort4 u = ((const ushort4*)(y + (size_t)row * EMB))[tid];
  float vx = b2f(u.x), vy = b2f(u.y), vz = b2f(u.z), vw = b2f(u.w);
  float s = vx + vy + vz + vw;
  float s2 = vx * vx + vy * vy + vz * vz + vw * vw;
#pragma unroll
  for (int m = 1; m < 64; m <<= 1) {
    s += __shfl_xor(s, m);
    s2 += __shfl_xor(s2, m);
  }
  __shared__ float rs_[4], rq_[4];
  if (lane == 0) { rs_[w] = s; rq_[w] = s2; }
  __syncthreads();
  s = rs_[0] + rs_[1] + rs_[2] + rs_[3];
  s2 = rq_[0] + rq_[1] + rq_[2] + rq_[3];
  const float mu = s * (1.f / EMB);
  const float var = s2 * (1.f / EMB) - mu * mu;
  const float rstd = rsqrtf(var + 1e-5f);
  const float4 gg = ((const float4*)gw)[tid];
  const float4 bb = ((const float4*)bw)[tid];
  ushort4 ob = {f2b((vx - mu) * rstd * gg.x + bb.x),
                f2b((vy - mu) * rstd * gg.y + bb.y),
                f2b((vz - mu) * rstd * gg.z + bb.z),
                f2b((vw - mu) * rstd * gg.w + bb.w)};
  ((ushort4*)(hb + (size_t)row * EMB))[tid] = ob;
}

__global__ __launch_bounds__(256) void k_ln2(const u16* __restrict__ hb,
                                             const float* __restrict__ z,
                                             const float* __restrict__ gw,
                                             const float* __restrict__ bw,
                                             float* __restrict__ outp) {
  const int row = blockIdx.x, tid = threadIdx.x, lane = tid & 63, w = tid >> 6;
  ushort4 u = ((const ushort4*)(hb + (size_t)row * EMB))[tid];
  const float4 zz = ((const float4*)(z + (size_t)row * EMB))[tid];
  float vx = b2f(u.x) + zz.x, vy = b2f(u.y) + zz.y;
  float vz = b2f(u.z) + zz.z, vw = b2f(u.w) + zz.w;
  float s = vx + vy + vz + vw;
  float s2 = vx * vx + vy * vy + vz * vz + vw * vw;
#pragma unroll
  for (int m = 1; m < 64; m <<= 1) {
    s += __shfl_xor(s, m);
    s2 += __shfl_xor(s2, m);
  }
  __shared__ float rs_[4], rq_[4];
  if (lane == 0) { rs_[w] = s; rq_[w] = s2; }
  __syncthreads();
  s = rs_[0] + rs_[1] + rs_[2] + rs_[3];
  s2 = rq_[0] + rq_[1] + rq_[2] + rq_[3];
  const float mu = s * (1.f / EMB);
  const float var = s2 * (1.f / EMB) - mu * mu;
  const float rstd = rsqrtf(var + 1e-5f);
  const float4 gg = ((const float4*)gw)[tid];
  const float4 bb = ((const float4*)bw)[tid];
  float4 o;
  o.x = (vx - mu) * rstd * gg.x + bb.x;
  o.y = (vy - mu) * rstd * gg.y + bb.y;
  o.z = (vz - mu) * rstd * gg.z + bb.z;
  o.w = (vw - mu) * rstd * gg.w + bb.w;
  ((float4*)(outp + (size_t)row * EMB))[tid] = o;
}

extern "C" void kernel_launch(void* const* d_in, const int* in_sizes, int n_in,
                              void* d_out, int out_size, void* d_ws, size_t ws_size,
                              hipStream_t stream) {
  const float* x = (const float*)d_in[0];
  const float* Wq = (const float*)d_in[1];
  const float* Wk = (const float*)d_in[2];
  const float* Wv = (const float*)d_in[3];
  const float* Wo = (const float*)d_in[4];
  const float* bo = (const float*)d_in[5];
  const float* g1 = (const float*)d_in[6];
  const float* b1 = (const float*)d_in[7];
  const float* W1 = (const float*)d_in[8];
  const float* bf1 = (const float*)d_in[9];
  const float* W2 = (const float*)d_in[10];
  const float* bf2 = (const float*)d_in[11];
  const float* g2 = (const float*)d_in[12];
  const float* b2 = (const float*)d_in[13];
  float* out = (float*)d_out;

  char* ws = (char*)d_ws;
  size_t off = 0;
  auto alloc = [&](size_t bytes) {
    char* p = ws + off;
    off += (bytes + 255) & ~(size_t)255;
    return p;
  };
  u16* xb = (u16*)alloc((size_t)NTOK * EMB * 2);
  u16* wqkvT = (u16*)alloc((size_t)3072 * 1024 * 2);
  u16* qB = (u16*)alloc((size_t)NTOK * EMB * 2);
  u16* kB = (u16*)alloc((size_t)NTOK * EMB * 2);
  u16* vTB = (u16*)alloc((size_t)NTOK * EMB * 2);
  u16* woT = (u16*)alloc((size_t)1024 * 1024 * 2);
  u16* w1T = (u16*)alloc((size_t)4096 * 1024 * 2);
  u16* w2T = (u16*)alloc((size_t)1024 * 4096 * 2);
  u16* y = (u16*)alloc((size_t)NTOK * EMB * 2);   // bf16 residual y = x + attn@Wo + bo
  u16* ff1 = (u16*)alloc((size_t)NTOK * INNER * 2);
  // aliases over dead regions:
  u16* attn = xb;          // xb dead after QKV GEMM
  float* z = (float*)qB;   // spans qB+kB (33.6MB), dead after attention
  u16* hb = vTB;           // dead after attention

  // fused prep: x convert + 6 weight transposes
  k_prep<<<20480, 256, 0, stream>>>(x, Wq, Wk, Wv, Wo, W1, W2, xb, wqkvT, woT,
                                    w1T, w2T);
  // QKV projection: 256x256 4-phase (384 blocks)
  k_g256<0><<<(NTOK / 256) * (3072 / 256), 512, 0, stream>>>(
      xb, wqkvT, NTOK, 3072, 1024, qB, kB, vTB, nullptr, nullptr, nullptr);
  // attention
  k_attn<<<64 * 32, 256, 0, stream>>>(qB, kB, vTB, attn);
  // out proj + bias + residual -> y (bf16)
  k_gemm8<1><<<(NTOK / 256) * (1024 / 128), 512, 0, stream>>>(
      attn, woT, NTOK, 1024, 1024, y, nullptr, bo, x);
  // LN1 -> hb (bf16)
  k_ln1<<<NTOK, 256, 0, stream>>>(y, g1, b1, hb);
  // FFN1 + relu: 256x256 4-phase (512 blocks)
  k_g256<2><<<(NTOK / 256) * (4096 / 256), 512, 0, stream>>>(
      hb, w1T, NTOK, 4096, 1024, ff1, nullptr, nullptr, nullptr, bf1, nullptr);
  // FFN2 -> z (f32)
  k_gemm8<3><<<(NTOK / 256) * (1024 / 128), 512, 0, stream>>>(
      ff1, w2T, NTOK, 1024, 4096, nullptr, z, bf2, nullptr);
  // LN2 -> out
  k_ln2<<<NTOK, 256, 0, stream>>>(hb, z, g2, b2, out);
}